// Round 2
// baseline (2138.035 us; speedup 1.0000x reference)
//
#include <hip/hip_runtime.h>
#include <math.h>

#define BN_EPS 1e-5f

// ---------------- CSR build ----------------

__global__ void k_zero_i32(int* __restrict__ p, int n){
  int i = blockIdx.x*blockDim.x + threadIdx.x;
  int stride = gridDim.x*blockDim.x;
  for (; i<n; i+=stride) p[i]=0;
}

__global__ void k_count(const int* __restrict__ ei, int E, int* __restrict__ deg){
  int e = blockIdx.x*blockDim.x + threadIdx.x;
  int stride = gridDim.x*blockDim.x;
  for (; e<E; e+=stride){
    int dst = ei[(size_t)E + e];
    atomicAdd(&deg[dst], 1);
  }
}

__global__ void k_scan_block(const int* __restrict__ deg, int n, int* __restrict__ off, int* __restrict__ blocksum){
  __shared__ int s[256];
  int tid = threadIdx.x;
  int i = blockIdx.x*256 + tid;
  int v = (i<n) ? deg[i] : 0;
  s[tid]=v; __syncthreads();
  #pragma unroll
  for (int o=1;o<256;o<<=1){
    int t = (tid>=o)? s[tid-o] : 0;
    __syncthreads();
    s[tid]+=t;
    __syncthreads();
  }
  if (i<n) off[i] = s[tid]-v;
  if (tid==255) blocksum[blockIdx.x] = s[tid];
}

__global__ void k_scan_sums(const int* __restrict__ blocksum, int nb, int* __restrict__ blockoff){
  __shared__ int s[512];
  int tid = threadIdx.x;
  int v = (tid<nb)? blocksum[tid] : 0;
  s[tid]=v; __syncthreads();
  #pragma unroll
  for (int o=1;o<512;o<<=1){
    int t = (tid>=o)? s[tid-o] : 0;
    __syncthreads();
    s[tid]+=t;
    __syncthreads();
  }
  blockoff[tid] = s[tid]-v;
}

__global__ void k_add_off(int* __restrict__ off, const int* __restrict__ blockoff, int n){
  int i = blockIdx.x*blockDim.x + threadIdx.x;
  int stride = gridDim.x*blockDim.x;
  for (; i<n; i+=stride) off[i] += blockoff[i>>8];
}

__global__ void k_fill(const int* __restrict__ ei, int E, const int* __restrict__ off,
                       int* __restrict__ cursor, int* __restrict__ eidx){
  int e = blockIdx.x*blockDim.x + threadIdx.x;
  int stride = gridDim.x*blockDim.x;
  for (; e<E; e+=stride){
    int src = ei[e];
    int dst = ei[(size_t)E+e];
    int p = atomicAdd(&cursor[dst],1);
    eidx[off[dst]+p] = src;
  }
}

// one wave per node: mean of x[src] rows (128 ch = 64 lanes x float2)
__global__ void k_aggregate(const float* __restrict__ x, const int* __restrict__ off,
                            const int* __restrict__ deg, const int* __restrict__ eidx,
                            float* __restrict__ agg, int n){
  int wid = (blockIdx.x*blockDim.x + threadIdx.x) >> 6;
  int lane = threadIdx.x & 63;
  if (wid >= n) return;
  int o = off[wid], d = deg[wid];
  const float2* x2 = (const float2*)x;
  float ax=0.f, ay=0.f;
  for (int i=0;i<d;i++){
    int s = eidx[o+i];
    float2 v = x2[(size_t)s*64 + lane];
    ax += v.x; ay += v.y;
  }
  float inv = 1.f / (float)max(d,1);
  float2 r; r.x = ax*inv; r.y = ay*inv;
  ((float2*)agg)[(size_t)wid*64 + lane] = r;
}

// ---------------- GEMM: out[r][c] = sum_k A[r][k]*W[c][k] (+ seg2) + bias ----------------
// optional per-K-channel affine+relu on A load (fused BN of previous layer)
// emits per-row-tile partial sum / sumsq per output channel (deterministic)

__global__ __launch_bounds__(256) void k_gemm(
    const float* __restrict__ A0, const float* __restrict__ Wt0, const float* __restrict__ ssA0, int K0,
    const float* __restrict__ A1, const float* __restrict__ Wt1, const float* __restrict__ ssA1, int K1,
    const float* __restrict__ bias, float* __restrict__ out, int nrows, int hout,
    float* __restrict__ psum, float* __restrict__ psq)
{
  __shared__ float As[16][64];
  __shared__ float Bs[16][64];
  __shared__ float red[2][64][16];
  int tid = threadIdx.x;
  int tx = tid & 15, ty = tid >> 4;
  int rbase = blockIdx.x*64, cbase = blockIdx.y*64;
  float acc[4][4];
  #pragma unroll
  for (int i=0;i<4;i++)
    #pragma unroll
    for (int j=0;j<4;j++) acc[i][j]=0.f;

  int lrow = tid >> 2;          // 0..63
  int lk   = (tid & 3) * 4;     // 0,4,8,12

  #pragma unroll
  for (int seg=0; seg<2; seg++){
    const float* A  = seg ? A1  : A0;
    const float* W  = seg ? Wt1 : Wt0;
    const float* ss = seg ? ssA1: ssA0;
    int K = seg ? K1 : K0;
    if (!A) continue;
    const float* scv = ss;
    const float* shv = ss ? ss+K : (const float*)0;
    for (int kb=0; kb<K; kb+=16){
      int r = rbase + lrow;
      float4 av = make_float4(0.f,0.f,0.f,0.f);
      if (r < nrows){
        av = *(const float4*)(A + (size_t)r*K + kb + lk);
        if (ss){
          float* f = (float*)&av;
          #pragma unroll
          for (int j=0;j<4;j++){
            int k = kb+lk+j;
            f[j] = fmaxf(f[j]*scv[k] + shv[k], 0.f);
          }
        }
      }
      {
        float* f=(float*)&av;
        #pragma unroll
        for (int j=0;j<4;j++) As[lk+j][lrow] = f[j];
      }
      {
        float4 bv = *(const float4*)(W + (size_t)(cbase+lrow)*K + kb + lk);
        float* f=(float*)&bv;
        #pragma unroll
        for (int j=0;j<4;j++) Bs[lk+j][lrow] = f[j];
      }
      __syncthreads();
      #pragma unroll
      for (int kk=0;kk<16;kk++){
        float4 a4 = *(const float4*)&As[kk][ty*4];
        float4 b4 = *(const float4*)&Bs[kk][tx*4];
        const float* af=(const float*)&a4;
        const float* bf=(const float*)&b4;
        #pragma unroll
        for (int i=0;i<4;i++)
          #pragma unroll
          for (int j=0;j<4;j++)
            acc[i][j] = fmaf(af[i], bf[j], acc[i][j]);
      }
      __syncthreads();
    }
  }
  // epilogue: bias, store, partial BN stats
  float s[4]={0.f,0.f,0.f,0.f}, q[4]={0.f,0.f,0.f,0.f};
  #pragma unroll
  for (int i=0;i<4;i++){
    int r = rbase + ty*4 + i;
    float o4[4];
    #pragma unroll
    for (int j=0;j<4;j++){
      int c = cbase + tx*4 + j;
      o4[j] = acc[i][j] + bias[c];
    }
    if (r < nrows){
      *(float4*)(out + (size_t)r*hout + cbase + tx*4) = *(const float4*)o4;
      #pragma unroll
      for (int j=0;j<4;j++){ s[j]+=o4[j]; q[j]+=o4[j]*o4[j]; }
    }
  }
  #pragma unroll
  for (int j=0;j<4;j++){
    red[0][tx*4+j][ty]=s[j];
    red[1][tx*4+j][ty]=q[j];
  }
  __syncthreads();
  if (tid < 64){
    float t=0.f;
    #pragma unroll
    for (int u=0;u<16;u++) t += red[0][tid][u];
    psum[(size_t)blockIdx.x*hout + cbase + tid] = t;
  } else if (tid < 128){
    int c = tid-64;
    float t=0.f;
    #pragma unroll
    for (int u=0;u<16;u++) t += red[1][c][u];
    psq[(size_t)blockIdx.x*hout + cbase + c] = t;
  }
}

// fold partial stats -> per-channel scale/shift for fused BN on next load
__global__ void k_stats(const float* __restrict__ psum, const float* __restrict__ psq,
                        int rt, int h, float ninv,
                        const float* __restrict__ g, const float* __restrict__ b,
                        float* __restrict__ ss){
  int c = threadIdx.x;
  if (c >= h) return;
  float S=0.f, Q=0.f;
  for (int i=0;i<rt;i++){ S += psum[(size_t)i*h + c]; Q += psq[(size_t)i*h + c]; }
  float m = S*ninv;
  float v = fmaxf(Q*ninv - m*m, 0.f);
  float sc = g[c] * rsqrtf(v + BN_EPS);
  ss[c]   = sc;
  ss[h+c] = b[c] - m*sc;
}

// 64 -> 14 linear (weights staged in LDS), fused BN+relu on load, emits stats
__global__ __launch_bounds__(256) void k_lin3(const float* __restrict__ h3, const float* __restrict__ ss3,
     const float* __restrict__ W3, const float* __restrict__ b3,
     float* __restrict__ h4, int n, float* __restrict__ psum, float* __restrict__ psq){
  __shared__ float Ws[14*64];
  __shared__ float bs[14];
  __shared__ float sc[64], sh[64];
  __shared__ float redp[2][14][4];
  int tid=threadIdx.x;
  for (int i=tid;i<896;i+=256) Ws[i]=W3[i];
  if (tid<14) bs[tid]=b3[tid];
  if (tid<64){ sc[tid]=ss3[tid]; sh[tid]=ss3[64+tid]; }
  __syncthreads();
  int node = blockIdx.x*256 + tid;
  float o[14];
  #pragma unroll
  for (int hh=0;hh<14;hh++) o[hh]=0.f;
  if (node<n){
    const float4* ar = (const float4*)(h3 + (size_t)node*64);
    #pragma unroll
    for (int kv=0;kv<16;kv++){
      float4 v = ar[kv];
      const float* f=(const float*)&v;
      #pragma unroll
      for (int j=0;j<4;j++){
        int k=kv*4+j;
        float a = fmaxf(f[j]*sc[k]+sh[k], 0.f);
        #pragma unroll
        for (int hh=0;hh<14;hh++) o[hh] = fmaf(a, Ws[hh*64+k], o[hh]);
      }
    }
    #pragma unroll
    for (int hh=0;hh<14;hh++){ o[hh]+=bs[hh]; h4[(size_t)node*14+hh]=o[hh]; }
  }
  int lane = tid & 63, w = tid>>6;
  #pragma unroll
  for (int hh=0;hh<14;hh++){
    float sv = (node<n)? o[hh] : 0.f;
    float qv = sv*sv;
    #pragma unroll
    for (int offs=32;offs>0;offs>>=1){
      sv += __shfl_down(sv,offs,64);
      qv += __shfl_down(qv,offs,64);
    }
    if (lane==0){ redp[0][hh][w]=sv; redp[1][hh][w]=qv; }
  }
  __syncthreads();
  if (tid<14){
    float t=redp[0][tid][0]+redp[0][tid][1]+redp[0][tid][2]+redp[0][tid][3];
    psum[(size_t)blockIdx.x*14+tid]=t;
  } else if (tid>=64 && tid<78){
    int c=tid-64;
    float t=redp[1][c][0]+redp[1][c][1]+redp[1][c][2]+redp[1][c][3];
    psq[(size_t)blockIdx.x*14+c]=t;
  }
}

// 14 -> 2 + log_softmax
__global__ void k_final(const float* __restrict__ h4, const float* __restrict__ ss4,
   const float* __restrict__ W4, const float* __restrict__ b4, float* __restrict__ out, int n){
  int node = blockIdx.x*blockDim.x+threadIdx.x;
  if (node>=n) return;
  float z0=b4[0], z1=b4[1];
  #pragma unroll
  for (int j=0;j<14;j++){
    float a = fmaxf(h4[(size_t)node*14+j]*ss4[j]+ss4[14+j], 0.f);
    z0 = fmaf(a, W4[j],    z0);
    z1 = fmaf(a, W4[14+j], z1);
  }
  float m = fmaxf(z0,z1);
  float lse = m + logf(expf(z0-m)+expf(z1-m));
  out[(size_t)node*2]   = z0-lse;
  out[(size_t)node*2+1] = z1-lse;
}

extern "C" void kernel_launch(void* const* d_in, const int* in_sizes, int n_in,
                              void* d_out, int out_size, void* d_ws, size_t ws_size,
                              hipStream_t stream){
  const float* x    = (const float*)d_in[0];
  const int*   ei   = (const int*)d_in[1];          // int64 in ref -> int32 on device per harness
  const float* Wl   = (const float*)d_in[2];
  const float* bl   = (const float*)d_in[3];
  const float* Wr   = (const float*)d_in[4];
  const float* bn_g = (const float*)d_in[5];
  const float* bn_b = (const float*)d_in[6];
  const float* W1   = (const float*)d_in[7];
  const float* b1   = (const float*)d_in[8];
  const float* W2   = (const float*)d_in[9];
  const float* b2   = (const float*)d_in[10];
  const float* W3   = (const float*)d_in[11];
  const float* b3   = (const float*)d_in[12];
  const float* W4   = (const float*)d_in[13];
  const float* b4   = (const float*)d_in[14];
  const float* g1   = (const float*)d_in[15];
  const float* bb1  = (const float*)d_in[16];
  const float* g2   = (const float*)d_in[17];
  const float* bb2  = (const float*)d_in[18];
  const float* g3   = (const float*)d_in[19];
  const float* bb3  = (const float*)d_in[20];

  const int N = in_sizes[0]/128;
  const int E = in_sizes[1]/2;
  const int RT  = (N+63)/64;
  const int RT4 = (N+255)/256;
  const int NB  = (N+255)/256;

  char* p = (char*)d_ws;
  auto alloc = [&](size_t bytes)->void*{
    void* r = (void*)p;
    p += (bytes + 255) & ~(size_t)255;
    return r;
  };
  int* deg      = (int*)alloc((size_t)N*2*sizeof(int)); // deg + cursor contiguous
  int* cursor   = deg + N;
  int* off      = (int*)alloc((size_t)N*sizeof(int));
  int* blocksum = (int*)alloc(512*sizeof(int));
  int* blockoff = (int*)alloc(512*sizeof(int));
  int* eidx     = (int*)alloc((size_t)E*sizeof(int));
  float* agg    = (float*)alloc((size_t)N*128*sizeof(float)); // reused as h3
  float* h1     = (float*)alloc((size_t)N*256*sizeof(float)); // reused as h4
  float* h2     = (float*)alloc((size_t)N*256*sizeof(float));
  float* psum   = (float*)alloc((size_t)RT*256*sizeof(float));
  float* psq    = (float*)alloc((size_t)RT*256*sizeof(float));
  float* ssb    = (float*)alloc(4*512*sizeof(float));
  float* h3 = agg;
  float* h4 = h1;
  float* ss1=ssb, *ss2=ssb+512, *ss3=ssb+1024, *ss4=ssb+1536;
  const float ninv = 1.f/(float)N;

  // CSR build
  k_zero_i32<<<dim3(512), dim3(256), 0, stream>>>(deg, 2*N);
  k_count<<<dim3(1024), dim3(256), 0, stream>>>(ei, E, deg);
  k_scan_block<<<dim3(NB), dim3(256), 0, stream>>>(deg, N, off, blocksum);
  k_scan_sums<<<dim3(1), dim3(512), 0, stream>>>(blocksum, NB, blockoff);
  k_add_off<<<dim3(256), dim3(256), 0, stream>>>(off, blockoff, N);
  k_fill<<<dim3(1024), dim3(256), 0, stream>>>(ei, E, off, cursor, eidx);
  // mean aggregate
  k_aggregate<<<dim3((N+3)/4), dim3(256), 0, stream>>>(x, off, deg, eidx, agg, N);

  // SAGE: h1 = agg@Wl^T + bl + x@Wr^T   (+ stats)
  k_gemm<<<dim3(RT,4), dim3(256), 0, stream>>>(agg, Wl, (const float*)0, 128,
                                               x,   Wr, (const float*)0, 128,
                                               bl, h1, N, 256, psum, psq);
  k_stats<<<dim3(1), dim3(256), 0, stream>>>(psum, psq, RT, 256, ninv, bn_g, bn_b, ss1);

  // h2 = relu(bn(h1)) @ W1^T + b1
  k_gemm<<<dim3(RT,4), dim3(256), 0, stream>>>(h1, W1, ss1, 256,
                                               (const float*)0, (const float*)0, (const float*)0, 0,
                                               b1, h2, N, 256, psum, psq);
  k_stats<<<dim3(1), dim3(256), 0, stream>>>(psum, psq, RT, 256, ninv, g1, bb1, ss2);

  // h3 = relu(bn(h2)) @ W2^T + b2   (hout=64)
  k_gemm<<<dim3(RT,1), dim3(256), 0, stream>>>(h2, W2, ss2, 256,
                                               (const float*)0, (const float*)0, (const float*)0, 0,
                                               b2, h3, N, 64, psum, psq);
  k_stats<<<dim3(1), dim3(256), 0, stream>>>(psum, psq, RT, 64, ninv, g2, bb2, ss3);

  // h4 = relu(bn(h3)) @ W3^T + b3   (hout=14)
  k_lin3<<<dim3(RT4), dim3(256), 0, stream>>>(h3, ss3, W3, b3, h4, N, psum, psq);
  k_stats<<<dim3(1), dim3(256), 0, stream>>>(psum, psq, RT4, 14, ninv, g3, bb3, ss4);

  // out = log_softmax(relu(bn(h4)) @ W4^T + b4)
  k_final<<<dim3((N+255)/256), dim3(256), 0, stream>>>(h4, ss4, W4, b4, (float*)d_out, N);
}

// Round 3
// 858.594 us; speedup vs baseline: 2.4902x; 2.4902x over previous
//
#include <hip/hip_runtime.h>
#include <math.h>

#define BN_EPS 1e-5f
#define STAT_NB 64

// ---------------- CSR build ----------------

__global__ void k_zero_i32(int* __restrict__ p, int n){
  int i = blockIdx.x*blockDim.x + threadIdx.x;
  int stride = gridDim.x*blockDim.x;
  for (; i<n; i+=stride) p[i]=0;
}

__global__ void k_count(const int* __restrict__ ei, int E, int* __restrict__ deg){
  int e = blockIdx.x*blockDim.x + threadIdx.x;
  int stride = gridDim.x*blockDim.x;
  for (; e<E; e+=stride){
    int dst = ei[(size_t)E + e];
    atomicAdd(&deg[dst], 1);
  }
}

__global__ void k_scan_block(const int* __restrict__ deg, int n, int* __restrict__ off, int* __restrict__ blocksum){
  __shared__ int s[256];
  int tid = threadIdx.x;
  int i = blockIdx.x*256 + tid;
  int v = (i<n) ? deg[i] : 0;
  s[tid]=v; __syncthreads();
  #pragma unroll
  for (int o=1;o<256;o<<=1){
    int t = (tid>=o)? s[tid-o] : 0;
    __syncthreads();
    s[tid]+=t;
    __syncthreads();
  }
  if (i<n) off[i] = s[tid]-v;
  if (tid==255) blocksum[blockIdx.x] = s[tid];
}

__global__ void k_scan_sums(const int* __restrict__ blocksum, int nb, int* __restrict__ blockoff){
  __shared__ int s[512];
  int tid = threadIdx.x;
  int v = (tid<nb)? blocksum[tid] : 0;
  s[tid]=v; __syncthreads();
  #pragma unroll
  for (int o=1;o<512;o<<=1){
    int t = (tid>=o)? s[tid-o] : 0;
    __syncthreads();
    s[tid]+=t;
    __syncthreads();
  }
  blockoff[tid] = s[tid]-v;
}

__global__ void k_add_off(int* __restrict__ off, const int* __restrict__ blockoff, int n){
  int i = blockIdx.x*blockDim.x + threadIdx.x;
  int stride = gridDim.x*blockDim.x;
  for (; i<n; i+=stride) off[i] += blockoff[i>>8];
}

__global__ void k_fill(const int* __restrict__ ei, int E, const int* __restrict__ off,
                       int* __restrict__ cursor, int* __restrict__ eidx){
  int e = blockIdx.x*blockDim.x + threadIdx.x;
  int stride = gridDim.x*blockDim.x;
  for (; e<E; e+=stride){
    int src = ei[e];
    int dst = ei[(size_t)E+e];
    int p = atomicAdd(&cursor[dst],1);
    eidx[off[dst]+p] = src;
  }
}

// one wave per node: mean of x[src] rows (128 ch = 64 lanes x float2)
__global__ void k_aggregate(const float* __restrict__ x, const int* __restrict__ off,
                            const int* __restrict__ deg, const int* __restrict__ eidx,
                            float* __restrict__ agg, int n){
  int wid = (blockIdx.x*blockDim.x + threadIdx.x) >> 6;
  int lane = threadIdx.x & 63;
  if (wid >= n) return;
  int o = off[wid], d = deg[wid];
  const float2* x2 = (const float2*)x;
  float ax=0.f, ay=0.f;
  for (int i=0;i<d;i++){
    int s = eidx[o+i];
    float2 v = x2[(size_t)s*64 + lane];
    ax += v.x; ay += v.y;
  }
  float inv = 1.f / (float)max(d,1);
  float2 r; r.x = ax*inv; r.y = ay*inv;
  ((float2*)agg)[(size_t)wid*64 + lane] = r;
}

// ---------------- GEMM: out[r][c] = sum_k A[r][k]*W[c][k] (+ seg2) + bias ----------------
// optional per-K-channel affine+relu on A load (fused BN of previous layer)
// emits per-row-tile partial sum / sumsq per output channel (deterministic)

__global__ __launch_bounds__(256) void k_gemm(
    const float* __restrict__ A0, const float* __restrict__ Wt0, const float* __restrict__ ssA0, int K0,
    const float* __restrict__ A1, const float* __restrict__ Wt1, const float* __restrict__ ssA1, int K1,
    const float* __restrict__ bias, float* __restrict__ out, int nrows, int hout,
    float* __restrict__ psum, float* __restrict__ psq)
{
  __shared__ float As[16][64];
  __shared__ float Bs[16][64];
  __shared__ float red[2][64][16];
  int tid = threadIdx.x;
  int tx = tid & 15, ty = tid >> 4;
  int rbase = blockIdx.x*64, cbase = blockIdx.y*64;
  float acc[4][4];
  #pragma unroll
  for (int i=0;i<4;i++)
    #pragma unroll
    for (int j=0;j<4;j++) acc[i][j]=0.f;

  int lrow = tid >> 2;          // 0..63
  int lk   = (tid & 3) * 4;     // 0,4,8,12

  #pragma unroll
  for (int seg=0; seg<2; seg++){
    const float* A  = seg ? A1  : A0;
    const float* W  = seg ? Wt1 : Wt0;
    const float* ss = seg ? ssA1: ssA0;
    int K = seg ? K1 : K0;
    if (!A) continue;
    const float* scv = ss;
    const float* shv = ss ? ss+K : (const float*)0;
    for (int kb=0; kb<K; kb+=16){
      int r = rbase + lrow;
      float4 av = make_float4(0.f,0.f,0.f,0.f);
      if (r < nrows){
        av = *(const float4*)(A + (size_t)r*K + kb + lk);
        if (ss){
          float* f = (float*)&av;
          #pragma unroll
          for (int j=0;j<4;j++){
            int k = kb+lk+j;
            f[j] = fmaxf(f[j]*scv[k] + shv[k], 0.f);
          }
        }
      }
      {
        float* f=(float*)&av;
        #pragma unroll
        for (int j=0;j<4;j++) As[lk+j][lrow] = f[j];
      }
      {
        float4 bv = *(const float4*)(W + (size_t)(cbase+lrow)*K + kb + lk);
        float* f=(float*)&bv;
        #pragma unroll
        for (int j=0;j<4;j++) Bs[lk+j][lrow] = f[j];
      }
      __syncthreads();
      #pragma unroll
      for (int kk=0;kk<16;kk++){
        float4 a4 = *(const float4*)&As[kk][ty*4];
        float4 b4 = *(const float4*)&Bs[kk][tx*4];
        const float* af=(const float*)&a4;
        const float* bf=(const float*)&b4;
        #pragma unroll
        for (int i=0;i<4;i++)
          #pragma unroll
          for (int j=0;j<4;j++)
            acc[i][j] = fmaf(af[i], bf[j], acc[i][j]);
      }
      __syncthreads();
    }
  }
  // epilogue: bias, store, partial BN stats
  float s[4]={0.f,0.f,0.f,0.f}, q[4]={0.f,0.f,0.f,0.f};
  #pragma unroll
  for (int i=0;i<4;i++){
    int r = rbase + ty*4 + i;
    float o4[4];
    #pragma unroll
    for (int j=0;j<4;j++){
      int c = cbase + tx*4 + j;
      o4[j] = acc[i][j] + bias[c];
    }
    if (r < nrows){
      *(float4*)(out + (size_t)r*hout + cbase + tx*4) = *(const float4*)o4;
      #pragma unroll
      for (int j=0;j<4;j++){ s[j]+=o4[j]; q[j]+=o4[j]*o4[j]; }
    }
  }
  #pragma unroll
  for (int j=0;j<4;j++){
    red[0][tx*4+j][ty]=s[j];
    red[1][tx*4+j][ty]=q[j];
  }
  __syncthreads();
  if (tid < 64){
    float t=0.f;
    #pragma unroll
    for (int u=0;u<16;u++) t += red[0][tid][u];
    psum[(size_t)blockIdx.x*hout + cbase + tid] = t;
  } else if (tid < 128){
    int c = tid-64;
    float t=0.f;
    #pragma unroll
    for (int u=0;u<16;u++) t += red[1][c][u];
    psq[(size_t)blockIdx.x*hout + cbase + c] = t;
  }
}

// ---- two-stage deterministic stats fold (fixes the 500us single-block serial reduce) ----

// stage A: block b reduces its row-chunk of psum/psq -> part[b][0][c], part[b][1][c]
__global__ __launch_bounds__(256) void k_stats_part(
    const float* __restrict__ psum, const float* __restrict__ psq,
    int rt, int h, float* __restrict__ part){
  int c = threadIdx.x;
  int b = blockIdx.x;
  if (c >= h) return;
  int chunk = (rt + STAT_NB - 1)/STAT_NB;
  int i0 = b*chunk;
  int i1 = min(rt, i0+chunk);
  float s0=0.f,s1=0.f,s2=0.f,s3=0.f, q0=0.f,q1=0.f,q2=0.f,q3=0.f;
  int i=i0;
  for (; i+3<i1; i+=4){
    s0 += psum[(size_t)i*h+c];     q0 += psq[(size_t)i*h+c];
    s1 += psum[(size_t)(i+1)*h+c]; q1 += psq[(size_t)(i+1)*h+c];
    s2 += psum[(size_t)(i+2)*h+c]; q2 += psq[(size_t)(i+2)*h+c];
    s3 += psum[(size_t)(i+3)*h+c]; q3 += psq[(size_t)(i+3)*h+c];
  }
  for (; i<i1; ++i){ s0 += psum[(size_t)i*h+c]; q0 += psq[(size_t)i*h+c]; }
  part[((size_t)b*2  )*h + c] = (s0+s1)+(s2+s3);
  part[((size_t)b*2+1)*h + c] = (q0+q1)+(q2+q3);
}

// stage B: fold STAT_NB partials -> per-channel scale/shift
__global__ void k_stats_fold(const float* __restrict__ part, int h, float ninv,
                             const float* __restrict__ g, const float* __restrict__ b_,
                             float* __restrict__ ss){
  int c = threadIdx.x;
  if (c >= h) return;
  float S0=0.f,S1=0.f,Q0=0.f,Q1=0.f;
  #pragma unroll 2
  for (int b=0;b<STAT_NB;b+=2){
    S0 += part[((size_t)b*2  )*h + c];
    Q0 += part[((size_t)b*2+1)*h + c];
    S1 += part[((size_t)(b+1)*2  )*h + c];
    Q1 += part[((size_t)(b+1)*2+1)*h + c];
  }
  float S = S0+S1, Q = Q0+Q1;
  float m = S*ninv;
  float v = fmaxf(Q*ninv - m*m, 0.f);
  float sc = g[c] * rsqrtf(v + BN_EPS);
  ss[c]   = sc;
  ss[h+c] = b_[c] - m*sc;
}

// 64 -> 14 linear (weights staged in LDS), fused BN+relu on load, emits stats
__global__ __launch_bounds__(256) void k_lin3(const float* __restrict__ h3, const float* __restrict__ ss3,
     const float* __restrict__ W3, const float* __restrict__ b3,
     float* __restrict__ h4, int n, float* __restrict__ psum, float* __restrict__ psq){
  __shared__ float Ws[14*64];
  __shared__ float bs[14];
  __shared__ float sc[64], sh[64];
  __shared__ float redp[2][14][4];
  int tid=threadIdx.x;
  for (int i=tid;i<896;i+=256) Ws[i]=W3[i];
  if (tid<14) bs[tid]=b3[tid];
  if (tid<64){ sc[tid]=ss3[tid]; sh[tid]=ss3[64+tid]; }
  __syncthreads();
  int node = blockIdx.x*256 + tid;
  float o[14];
  #pragma unroll
  for (int hh=0;hh<14;hh++) o[hh]=0.f;
  if (node<n){
    const float4* ar = (const float4*)(h3 + (size_t)node*64);
    #pragma unroll
    for (int kv=0;kv<16;kv++){
      float4 v = ar[kv];
      const float* f=(const float*)&v;
      #pragma unroll
      for (int j=0;j<4;j++){
        int k=kv*4+j;
        float a = fmaxf(f[j]*sc[k]+sh[k], 0.f);
        #pragma unroll
        for (int hh=0;hh<14;hh++) o[hh] = fmaf(a, Ws[hh*64+k], o[hh]);
      }
    }
    #pragma unroll
    for (int hh=0;hh<14;hh++){ o[hh]+=bs[hh]; h4[(size_t)node*14+hh]=o[hh]; }
  }
  int lane = tid & 63, w = tid>>6;
  #pragma unroll
  for (int hh=0;hh<14;hh++){
    float sv = (node<n)? o[hh] : 0.f;
    float qv = sv*sv;
    #pragma unroll
    for (int offs=32;offs>0;offs>>=1){
      sv += __shfl_down(sv,offs,64);
      qv += __shfl_down(qv,offs,64);
    }
    if (lane==0){ redp[0][hh][w]=sv; redp[1][hh][w]=qv; }
  }
  __syncthreads();
  if (tid<14){
    float t=redp[0][tid][0]+redp[0][tid][1]+redp[0][tid][2]+redp[0][tid][3];
    psum[(size_t)blockIdx.x*14+tid]=t;
  } else if (tid>=64 && tid<78){
    int c=tid-64;
    float t=redp[1][c][0]+redp[1][c][1]+redp[1][c][2]+redp[1][c][3];
    psq[(size_t)blockIdx.x*14+c]=t;
  }
}

// 14 -> 2 + log_softmax
__global__ void k_final(const float* __restrict__ h4, const float* __restrict__ ss4,
   const float* __restrict__ W4, const float* __restrict__ b4, float* __restrict__ out, int n){
  int node = blockIdx.x*blockDim.x+threadIdx.x;
  if (node>=n) return;
  float z0=b4[0], z1=b4[1];
  #pragma unroll
  for (int j=0;j<14;j++){
    float a = fmaxf(h4[(size_t)node*14+j]*ss4[j]+ss4[14+j], 0.f);
    z0 = fmaf(a, W4[j],    z0);
    z1 = fmaf(a, W4[14+j], z1);
  }
  float m = fmaxf(z0,z1);
  float lse = m + logf(expf(z0-m)+expf(z1-m));
  out[(size_t)node*2]   = z0-lse;
  out[(size_t)node*2+1] = z1-lse;
}

extern "C" void kernel_launch(void* const* d_in, const int* in_sizes, int n_in,
                              void* d_out, int out_size, void* d_ws, size_t ws_size,
                              hipStream_t stream){
  const float* x    = (const float*)d_in[0];
  const int*   ei   = (const int*)d_in[1];          // int64 in ref -> int32 on device per harness
  const float* Wl   = (const float*)d_in[2];
  const float* bl   = (const float*)d_in[3];
  const float* Wr   = (const float*)d_in[4];
  const float* bn_g = (const float*)d_in[5];
  const float* bn_b = (const float*)d_in[6];
  const float* W1   = (const float*)d_in[7];
  const float* b1   = (const float*)d_in[8];
  const float* W2   = (const float*)d_in[9];
  const float* b2   = (const float*)d_in[10];
  const float* W3   = (const float*)d_in[11];
  const float* b3   = (const float*)d_in[12];
  const float* W4   = (const float*)d_in[13];
  const float* b4   = (const float*)d_in[14];
  const float* g1   = (const float*)d_in[15];
  const float* bb1  = (const float*)d_in[16];
  const float* g2   = (const float*)d_in[17];
  const float* bb2  = (const float*)d_in[18];
  const float* g3   = (const float*)d_in[19];
  const float* bb3  = (const float*)d_in[20];

  const int N = in_sizes[0]/128;
  const int E = in_sizes[1]/2;
  const int RT  = (N+63)/64;
  const int RT4 = (N+255)/256;
  const int NB  = (N+255)/256;

  char* p = (char*)d_ws;
  auto alloc = [&](size_t bytes)->void*{
    void* r = (void*)p;
    p += (bytes + 255) & ~(size_t)255;
    return r;
  };
  int* deg      = (int*)alloc((size_t)N*2*sizeof(int)); // deg + cursor contiguous
  int* cursor   = deg + N;
  int* off      = (int*)alloc((size_t)N*sizeof(int));
  int* blocksum = (int*)alloc(512*sizeof(int));
  int* blockoff = (int*)alloc(512*sizeof(int));
  int* eidx     = (int*)alloc((size_t)E*sizeof(int));
  float* agg    = (float*)alloc((size_t)N*128*sizeof(float)); // reused as h3
  float* h1     = (float*)alloc((size_t)N*256*sizeof(float)); // reused as h4
  float* h2     = (float*)alloc((size_t)N*256*sizeof(float));
  float* psum   = (float*)alloc((size_t)RT*256*sizeof(float));
  float* psq    = (float*)alloc((size_t)RT*256*sizeof(float));
  float* part   = (float*)alloc((size_t)STAT_NB*2*256*sizeof(float));
  float* ssb    = (float*)alloc(4*512*sizeof(float));
  float* h3 = agg;
  float* h4 = h1;
  float* ss1=ssb, *ss2=ssb+512, *ss3=ssb+1024, *ss4=ssb+1536;
  const float ninv = 1.f/(float)N;

  // CSR build
  k_zero_i32<<<dim3(512), dim3(256), 0, stream>>>(deg, 2*N);
  k_count<<<dim3(1024), dim3(256), 0, stream>>>(ei, E, deg);
  k_scan_block<<<dim3(NB), dim3(256), 0, stream>>>(deg, N, off, blocksum);
  k_scan_sums<<<dim3(1), dim3(512), 0, stream>>>(blocksum, NB, blockoff);
  k_add_off<<<dim3(256), dim3(256), 0, stream>>>(off, blockoff, N);
  k_fill<<<dim3(1024), dim3(256), 0, stream>>>(ei, E, off, cursor, eidx);
  // mean aggregate
  k_aggregate<<<dim3((N+3)/4), dim3(256), 0, stream>>>(x, off, deg, eidx, agg, N);

  // SAGE: h1 = agg@Wl^T + bl + x@Wr^T   (+ stats)
  k_gemm<<<dim3(RT,4), dim3(256), 0, stream>>>(agg, Wl, (const float*)0, 128,
                                               x,   Wr, (const float*)0, 128,
                                               bl, h1, N, 256, psum, psq);
  k_stats_part<<<dim3(STAT_NB), dim3(256), 0, stream>>>(psum, psq, RT, 256, part);
  k_stats_fold<<<dim3(1), dim3(256), 0, stream>>>(part, 256, ninv, bn_g, bn_b, ss1);

  // h2 = relu(bn(h1)) @ W1^T + b1
  k_gemm<<<dim3(RT,4), dim3(256), 0, stream>>>(h1, W1, ss1, 256,
                                               (const float*)0, (const float*)0, (const float*)0, 0,
                                               b1, h2, N, 256, psum, psq);
  k_stats_part<<<dim3(STAT_NB), dim3(256), 0, stream>>>(psum, psq, RT, 256, part);
  k_stats_fold<<<dim3(1), dim3(256), 0, stream>>>(part, 256, ninv, g1, bb1, ss2);

  // h3 = relu(bn(h2)) @ W2^T + b2   (hout=64)
  k_gemm<<<dim3(RT,1), dim3(256), 0, stream>>>(h2, W2, ss2, 256,
                                               (const float*)0, (const float*)0, (const float*)0, 0,
                                               b2, h3, N, 64, psum, psq);
  k_stats_part<<<dim3(STAT_NB), dim3(256), 0, stream>>>(psum, psq, RT, 64, part);
  k_stats_fold<<<dim3(1), dim3(64), 0, stream>>>(part, 64, ninv, g2, bb2, ss3);

  // h4 = relu(bn(h3)) @ W3^T + b3   (hout=14)
  k_lin3<<<dim3(RT4), dim3(256), 0, stream>>>(h3, ss3, W3, b3, h4, N, psum, psq);
  k_stats_part<<<dim3(STAT_NB), dim3(256), 0, stream>>>(psum, psq, RT4, 14, part);
  k_stats_fold<<<dim3(1), dim3(64), 0, stream>>>(part, 14, ninv, g3, bb3, ss4);

  // out = log_softmax(relu(bn(h4)) @ W4^T + b4)
  k_final<<<dim3((N+255)/256), dim3(256), 0, stream>>>(h4, ss4, W4, b4, (float*)d_out, N);
}

// Round 4
// 520.863 us; speedup vs baseline: 4.1048x; 1.6484x over previous
//
#include <hip/hip_runtime.h>
#include <math.h>

#define BN_EPS 1e-5f
#define STAT_NB 64

typedef unsigned short u16;
typedef __attribute__((ext_vector_type(8))) unsigned short u16x8;
typedef __attribute__((ext_vector_type(8))) short bf16x8;
typedef __attribute__((ext_vector_type(4))) float f32x4;

__device__ __forceinline__ float bf2f(u16 b){
  union{unsigned int u; float f;} c; c.u = ((unsigned int)b)<<16; return c.f;
}
__device__ __forceinline__ u16 f2bf(float f){
  union{float f; unsigned int u;} c; c.f=f;
  unsigned int u = c.u;
  return (u16)((u + 0x7fffu + ((u>>16)&1u)) >> 16);
}

// ---------------- CSR build ----------------

__global__ void k_zero_i32(int* __restrict__ p, int n){
  int i = blockIdx.x*blockDim.x + threadIdx.x;
  int stride = gridDim.x*blockDim.x;
  for (; i<n; i+=stride) p[i]=0;
}

__global__ void k_count(const int* __restrict__ ei, int E, int* __restrict__ deg){
  int e = blockIdx.x*blockDim.x + threadIdx.x;
  int stride = gridDim.x*blockDim.x;
  for (; e<E; e+=stride){
    int dst = ei[(size_t)E + e];
    atomicAdd(&deg[dst], 1);
  }
}

__global__ void k_scan_block(const int* __restrict__ deg, int n, int* __restrict__ off, int* __restrict__ blocksum){
  __shared__ int s[256];
  int tid = threadIdx.x;
  int i = blockIdx.x*256 + tid;
  int v = (i<n) ? deg[i] : 0;
  s[tid]=v; __syncthreads();
  #pragma unroll
  for (int o=1;o<256;o<<=1){
    int t = (tid>=o)? s[tid-o] : 0;
    __syncthreads();
    s[tid]+=t;
    __syncthreads();
  }
  if (i<n) off[i] = s[tid]-v;
  if (tid==255) blocksum[blockIdx.x] = s[tid];
}

__global__ void k_scan_sums(const int* __restrict__ blocksum, int nb, int* __restrict__ blockoff){
  __shared__ int s[512];
  int tid = threadIdx.x;
  int v = (tid<nb)? blocksum[tid] : 0;
  s[tid]=v; __syncthreads();
  #pragma unroll
  for (int o=1;o<512;o<<=1){
    int t = (tid>=o)? s[tid-o] : 0;
    __syncthreads();
    s[tid]+=t;
    __syncthreads();
  }
  blockoff[tid] = s[tid]-v;
}

__global__ void k_add_off(int* __restrict__ off, const int* __restrict__ blockoff, int n){
  int i = blockIdx.x*blockDim.x + threadIdx.x;
  int stride = gridDim.x*blockDim.x;
  for (; i<n; i+=stride) off[i] += blockoff[i>>8];
}

__global__ void k_fill(const int* __restrict__ ei, int E, const int* __restrict__ off,
                       int* __restrict__ cursor, int* __restrict__ eidx){
  int e = blockIdx.x*blockDim.x + threadIdx.x;
  int stride = gridDim.x*blockDim.x;
  for (; e<E; e+=stride){
    int src = ei[e];
    int dst = ei[(size_t)E+e];
    int p = atomicAdd(&cursor[dst],1);
    eidx[off[dst]+p] = src;
  }
}

// ---------------- dtype conversion ----------------

// x fp32 [n][128] -> Acat[:,128:256] bf16 (row stride 256)
__global__ void k_cvt_x(const float* __restrict__ x, u16* __restrict__ Acat, int n){
  int i = blockIdx.x*blockDim.x + threadIdx.x;  // one per 8 elems
  int total = n*16;
  int stride = gridDim.x*blockDim.x;
  for (; i<total; i+=stride){
    int r = i>>4, kb = (i&15)*8;
    const float4* src = (const float4*)(x + (size_t)r*128 + kb);
    float4 a = src[0], b = src[1];
    u16x8 v;
    v[0]=f2bf(a.x); v[1]=f2bf(a.y); v[2]=f2bf(a.z); v[3]=f2bf(a.w);
    v[4]=f2bf(b.x); v[5]=f2bf(b.y); v[6]=f2bf(b.z); v[7]=f2bf(b.w);
    *(u16x8*)(Acat + (size_t)r*256 + 128 + kb) = v;
  }
}

// generic fp32 -> bf16 (flat)
__global__ void k_cvt_w(const float* __restrict__ w, u16* __restrict__ wb, int total8){
  int i = blockIdx.x*blockDim.x + threadIdx.x;
  int stride = gridDim.x*blockDim.x;
  for (; i<total8; i+=stride){
    const float4* src = (const float4*)(w + (size_t)i*8);
    float4 a = src[0], b = src[1];
    u16x8 v;
    v[0]=f2bf(a.x); v[1]=f2bf(a.y); v[2]=f2bf(a.z); v[3]=f2bf(a.w);
    v[4]=f2bf(b.x); v[5]=f2bf(b.y); v[6]=f2bf(b.z); v[7]=f2bf(b.w);
    *(u16x8*)(wb + (size_t)i*8) = v;
  }
}

// Wb1[c][k] = k<128 ? Wl[c][k] : Wr[c][k-128]   (c in [0,256))
__global__ void k_cvt_cat(const float* __restrict__ Wl, const float* __restrict__ Wr,
                          u16* __restrict__ Wb1){
  int i = blockIdx.x*blockDim.x + threadIdx.x;  // per 8 elems, total 256*256/8=8192
  if (i >= 8192) return;
  int c = i>>5, kb = (i&31)*8;
  const float* src = (kb<128) ? (Wl + (size_t)c*128 + kb) : (Wr + (size_t)c*128 + kb-128);
  float4 a = ((const float4*)src)[0], b = ((const float4*)src)[1];
  u16x8 v;
  v[0]=f2bf(a.x); v[1]=f2bf(a.y); v[2]=f2bf(a.z); v[3]=f2bf(a.w);
  v[4]=f2bf(b.x); v[5]=f2bf(b.y); v[6]=f2bf(b.z); v[7]=f2bf(b.w);
  *(u16x8*)(Wb1 + (size_t)c*256 + kb) = v;
}

// one wave per node: mean of bf16 rows Acat[s][128:256] -> Acat[wid][0:128]
__global__ void k_aggregate(u16* Acat, const int* __restrict__ off,
                            const int* __restrict__ deg, const int* __restrict__ eidx, int n){
  int wid = (blockIdx.x*blockDim.x + threadIdx.x) >> 6;
  int lane = threadIdx.x & 63;
  if (wid >= n) return;
  int o = off[wid], d = deg[wid];
  float ax=0.f, ay=0.f;
  for (int i=0;i<d;i++){
    int s = eidx[o+i];
    unsigned int v = *(const unsigned int*)(Acat + (size_t)s*256 + 128 + lane*2);
    ax += bf2f((u16)(v & 0xffffu));
    ay += bf2f((u16)(v >> 16));
  }
  float inv = 1.f / (float)max(d,1);
  unsigned int r = (unsigned int)f2bf(ax*inv) | ((unsigned int)f2bf(ay*inv) << 16);
  *(unsigned int*)(Acat + (size_t)wid*256 + lane*2) = r;
}

// ---------------- bf16 MFMA GEMM ----------------
// out[r][c] = sum_k relu?(bn?(A[r][k])) * W[c][k] + bias[c], K=256 fixed
// A,W,out bf16; stats (fp32) emitted per 128-row block.
// tile 128 x COLS, 4 waves (2x2), BK=64, XOR-swizzled LDS (slot ^= row&7).

template<int COLS>
__global__ __launch_bounds__(256) void k_gemm_mfma(
    const u16* __restrict__ A, const u16* __restrict__ W,
    const float* __restrict__ ss, int has_ss,
    const float* __restrict__ bias, u16* __restrict__ out,
    int nrows, int hout,
    float* __restrict__ psum, float* __restrict__ psq)
{
  constexpr int WN  = COLS/2;   // per-wave cols
  constexpr int NFR = WN/16;    // n-fragments per wave
  __shared__ u16 As[128*64];
  __shared__ u16 Bs[COLS*64];
  __shared__ float scs[256], shs[256];
  __shared__ float red[2][2][COLS];

  int tid  = threadIdx.x;
  int lane = tid & 63, wave = tid >> 6;
  int wr = wave >> 1, wc = wave & 1;
  int rbase = blockIdx.x*128, cbase = blockIdx.y*COLS;

  if (has_ss){ scs[tid] = ss[tid]; shs[tid] = ss[256+tid]; }
  __syncthreads();

  f32x4 acc[4][NFR];
  #pragma unroll
  for (int m=0;m<4;m++)
    #pragma unroll
    for (int n=0;n<NFR;n++)
      acc[m][n] = (f32x4){0.f,0.f,0.f,0.f};

  // A staging: thread -> (row, 32-col half); 4 x u16x8 per K-tile
  int arow = tid >> 1;
  int acb  = (tid & 1) * 32;
  bool avalid = (rbase + arow) < nrows;
  const u16* aptr = A + (size_t)(rbase+arow)*256 + acb;
  // B staging
  int brow, bcb;
  if (COLS==128){ brow = tid>>1; bcb = (tid&1)*32; }
  else          { brow = tid>>2; bcb = (tid&3)*16; }
  const u16* bptr = W + (size_t)(cbase+brow)*256 + bcb;

  for (int kt=0; kt<256; kt+=64){
    #pragma unroll
    for (int q=0;q<4;q++){
      u16x8 v = (u16x8){0,0,0,0,0,0,0,0};
      if (avalid) v = *(const u16x8*)(aptr + kt + q*8);
      if (has_ss){
        int k = acb + q*8;  // absolute k = kt + k
        #pragma unroll
        for (int e=0;e<8;e++){
          float f = bf2f(v[e]);
          f = fmaxf(fmaf(f, scs[kt+k+e], shs[kt+k+e]), 0.f);
          v[e] = f2bf(f);
        }
      }
      int slot = ((acb>>3) + q) ^ (arow & 7);
      *(u16x8*)(As + arow*64 + slot*8) = v;
    }
    #pragma unroll
    for (int q=0;q<COLS/32;q++){
      u16x8 v = *(const u16x8*)(bptr + kt + q*8);
      int slot = ((bcb>>3) + q) ^ (brow & 7);
      *(u16x8*)(Bs + brow*64 + slot*8) = v;
    }
    __syncthreads();

    int fr = lane & 15, g = lane >> 4;
    #pragma unroll
    for (int kk=0;kk<2;kk++){
      bf16x8 af[4], bfr[NFR];
      #pragma unroll
      for (int m=0;m<4;m++){
        int row = wr*64 + m*16 + fr;
        int slot = (kk*4 + g) ^ (row & 7);
        af[m] = *(const bf16x8*)(As + row*64 + slot*8);
      }
      #pragma unroll
      for (int n=0;n<NFR;n++){
        int row = wc*WN + n*16 + fr;
        int slot = (kk*4 + g) ^ (row & 7);
        bfr[n] = *(const bf16x8*)(Bs + row*64 + slot*8);
      }
      #pragma unroll
      for (int m=0;m<4;m++)
        #pragma unroll
        for (int n=0;n<NFR;n++)
          acc[m][n] = __builtin_amdgcn_mfma_f32_16x16x32_bf16(af[m], bfr[n], acc[m][n], 0, 0, 0);
    }
    __syncthreads();
  }

  // epilogue: bias, bf16 store, BN partial stats
  int cl = lane & 15, g = lane >> 4;
  float bv[NFR], sn[NFR], qn[NFR];
  #pragma unroll
  for (int n=0;n<NFR;n++){
    bv[n] = bias[cbase + wc*WN + n*16 + cl];
    sn[n] = 0.f; qn[n] = 0.f;
  }
  #pragma unroll
  for (int m=0;m<4;m++){
    int r0 = rbase + wr*64 + m*16 + g*4;
    #pragma unroll
    for (int n=0;n<NFR;n++){
      int c = cbase + wc*WN + n*16 + cl;
      #pragma unroll
      for (int i=0;i<4;i++){
        int r = r0 + i;
        if (r < nrows){
          float v = acc[m][n][i] + bv[n];
          out[(size_t)r*hout + c] = f2bf(v);
          sn[n] += v; qn[n] += v*v;
        }
      }
    }
  }
  #pragma unroll
  for (int n=0;n<NFR;n++){
    sn[n] += __shfl_xor(sn[n], 16, 64);
    sn[n] += __shfl_xor(sn[n], 32, 64);
    qn[n] += __shfl_xor(qn[n], 16, 64);
    qn[n] += __shfl_xor(qn[n], 32, 64);
  }
  if (lane < 16){
    #pragma unroll
    for (int n=0;n<NFR;n++){
      int cc = wc*WN + n*16 + lane;
      red[0][wr][cc] = sn[n];
      red[1][wr][cc] = qn[n];
    }
  }
  __syncthreads();
  if (tid < COLS){
    psum[(size_t)blockIdx.x*hout + cbase + tid] = red[0][0][tid] + red[0][1][tid];
  } else if (tid < 2*COLS){
    int c = tid - COLS;
    psq[(size_t)blockIdx.x*hout + cbase + c] = red[1][0][c] + red[1][1][c];
  }
}

// ---- two-stage deterministic stats fold ----

__global__ __launch_bounds__(256) void k_stats_part(
    const float* __restrict__ psum, const float* __restrict__ psq,
    int rt, int h, float* __restrict__ part){
  int c = threadIdx.x;
  int b = blockIdx.x;
  if (c >= h) return;
  int chunk = (rt + STAT_NB - 1)/STAT_NB;
  int i0 = b*chunk;
  int i1 = min(rt, i0+chunk);
  float s0=0.f,s1=0.f,s2=0.f,s3=0.f, q0=0.f,q1=0.f,q2=0.f,q3=0.f;
  int i=i0;
  for (; i+3<i1; i+=4){
    s0 += psum[(size_t)i*h+c];     q0 += psq[(size_t)i*h+c];
    s1 += psum[(size_t)(i+1)*h+c]; q1 += psq[(size_t)(i+1)*h+c];
    s2 += psum[(size_t)(i+2)*h+c]; q2 += psq[(size_t)(i+2)*h+c];
    s3 += psum[(size_t)(i+3)*h+c]; q3 += psq[(size_t)(i+3)*h+c];
  }
  for (; i<i1; ++i){ s0 += psum[(size_t)i*h+c]; q0 += psq[(size_t)i*h+c]; }
  part[((size_t)b*2  )*h + c] = (s0+s1)+(s2+s3);
  part[((size_t)b*2+1)*h + c] = (q0+q1)+(q2+q3);
}

__global__ void k_stats_fold(const float* __restrict__ part, int h, float ninv,
                             const float* __restrict__ g, const float* __restrict__ b_,
                             float* __restrict__ ss){
  int c = threadIdx.x;
  if (c >= h) return;
  float S0=0.f,S1=0.f,Q0=0.f,Q1=0.f;
  #pragma unroll 2
  for (int b=0;b<STAT_NB;b+=2){
    S0 += part[((size_t)b*2  )*h + c];
    Q0 += part[((size_t)b*2+1)*h + c];
    S1 += part[((size_t)(b+1)*2  )*h + c];
    Q1 += part[((size_t)(b+1)*2+1)*h + c];
  }
  float S = S0+S1, Q = Q0+Q1;
  float m = S*ninv;
  float v = fmaxf(Q*ninv - m*m, 0.f);
  float sc = g[c] * rsqrtf(v + BN_EPS);
  ss[c]   = sc;
  ss[h+c] = b_[c] - m*sc;
}

// 64 -> 14 linear (bf16 input, weights in LDS), fused BN+relu, emits stats
__global__ __launch_bounds__(256) void k_lin3(const u16* __restrict__ h3, const float* __restrict__ ss3,
     const float* __restrict__ W3, const float* __restrict__ b3,
     float* __restrict__ h4, int n, float* __restrict__ psum, float* __restrict__ psq){
  __shared__ float Ws[14*64];
  __shared__ float bs[14];
  __shared__ float sc[64], sh[64];
  __shared__ float redp[2][14][4];
  int tid=threadIdx.x;
  for (int i=tid;i<896;i+=256) Ws[i]=W3[i];
  if (tid<14) bs[tid]=b3[tid];
  if (tid<64){ sc[tid]=ss3[tid]; sh[tid]=ss3[64+tid]; }
  __syncthreads();
  int node = blockIdx.x*256 + tid;
  float o[14];
  #pragma unroll
  for (int hh=0;hh<14;hh++) o[hh]=0.f;
  if (node<n){
    const u16x8* ar = (const u16x8*)(h3 + (size_t)node*64);
    #pragma unroll
    for (int kv=0;kv<8;kv++){
      u16x8 v = ar[kv];
      #pragma unroll
      for (int j=0;j<8;j++){
        int k=kv*8+j;
        float a = fmaxf(fmaf(bf2f(v[j]), sc[k], sh[k]), 0.f);
        #pragma unroll
        for (int hh=0;hh<14;hh++) o[hh] = fmaf(a, Ws[hh*64+k], o[hh]);
      }
    }
    #pragma unroll
    for (int hh=0;hh<14;hh++){ o[hh]+=bs[hh]; h4[(size_t)node*14+hh]=o[hh]; }
  }
  int lane = tid & 63, w = tid>>6;
  #pragma unroll
  for (int hh=0;hh<14;hh++){
    float sv = (node<n)? o[hh] : 0.f;
    float qv = sv*sv;
    #pragma unroll
    for (int offs=32;offs>0;offs>>=1){
      sv += __shfl_down(sv,offs,64);
      qv += __shfl_down(qv,offs,64);
    }
    if (lane==0){ redp[0][hh][w]=sv; redp[1][hh][w]=qv; }
  }
  __syncthreads();
  if (tid<14){
    float t=redp[0][tid][0]+redp[0][tid][1]+redp[0][tid][2]+redp[0][tid][3];
    psum[(size_t)blockIdx.x*14+tid]=t;
  } else if (tid>=64 && tid<78){
    int c=tid-64;
    float t=redp[1][c][0]+redp[1][c][1]+redp[1][c][2]+redp[1][c][3];
    psq[(size_t)blockIdx.x*14+c]=t;
  }
}

// 14 -> 2 + log_softmax
__global__ void k_final(const float* __restrict__ h4, const float* __restrict__ ss4,
   const float* __restrict__ W4, const float* __restrict__ b4, float* __restrict__ out, int n){
  int node = blockIdx.x*blockDim.x+threadIdx.x;
  if (node>=n) return;
  float z0=b4[0], z1=b4[1];
  #pragma unroll
  for (int j=0;j<14;j++){
    float a = fmaxf(h4[(size_t)node*14+j]*ss4[j]+ss4[14+j], 0.f);
    z0 = fmaf(a, W4[j],    z0);
    z1 = fmaf(a, W4[14+j], z1);
  }
  float m = fmaxf(z0,z1);
  float lse = m + logf(expf(z0-m)+expf(z1-m));
  out[(size_t)node*2]   = z0-lse;
  out[(size_t)node*2+1] = z1-lse;
}

extern "C" void kernel_launch(void* const* d_in, const int* in_sizes, int n_in,
                              void* d_out, int out_size, void* d_ws, size_t ws_size,
                              hipStream_t stream){
  const float* x    = (const float*)d_in[0];
  const int*   ei   = (const int*)d_in[1];          // int64 in ref -> int32 on device per harness
  const float* Wl   = (const float*)d_in[2];
  const float* bl   = (const float*)d_in[3];
  const float* Wr   = (const float*)d_in[4];
  const float* bn_g = (const float*)d_in[5];
  const float* bn_b = (const float*)d_in[6];
  const float* W1   = (const float*)d_in[7];
  const float* b1   = (const float*)d_in[8];
  const float* W2   = (const float*)d_in[9];
  const float* b2   = (const float*)d_in[10];
  const float* W3   = (const float*)d_in[11];
  const float* b3   = (const float*)d_in[12];
  const float* W4   = (const float*)d_in[13];
  const float* b4   = (const float*)d_in[14];
  const float* g1   = (const float*)d_in[15];
  const float* bb1  = (const float*)d_in[16];
  const float* g2   = (const float*)d_in[17];
  const float* bb2  = (const float*)d_in[18];
  const float* g3   = (const float*)d_in[19];
  const float* bb3  = (const float*)d_in[20];

  const int N = in_sizes[0]/128;
  const int E = in_sizes[1]/2;
  const int RT2 = (N+127)/128;   // 128-row GEMM tiles
  const int RT4 = (N+255)/256;   // lin3 blocks
  const int NB  = (N+255)/256;

  char* p = (char*)d_ws;
  auto alloc = [&](size_t bytes)->void*{
    void* r = (void*)p;
    p += (bytes + 255) & ~(size_t)255;
    return r;
  };
  int* deg      = (int*)alloc((size_t)N*2*sizeof(int)); // deg + cursor contiguous
  int* cursor   = deg + N;
  int* off      = (int*)alloc((size_t)N*sizeof(int));
  int* blocksum = (int*)alloc(512*sizeof(int));
  int* blockoff = (int*)alloc(512*sizeof(int));
  int* eidx     = (int*)alloc((size_t)E*sizeof(int));
  u16* Acat     = (u16*)alloc((size_t)N*256*sizeof(u16));  // [agg | x] bf16; reused as h2
  u16* h1b      = (u16*)alloc((size_t)N*256*sizeof(u16));  // gemm1 out; reused as h3
  float* h4     = (float*)alloc((size_t)N*14*sizeof(float));
  u16* Wb1      = (u16*)alloc(256*256*sizeof(u16));
  u16* Wb2      = (u16*)alloc(256*256*sizeof(u16));
  u16* Wb3      = (u16*)alloc(64*256*sizeof(u16));
  float* psum   = (float*)alloc((size_t)RT2*256*sizeof(float));
  float* psq    = (float*)alloc((size_t)RT2*256*sizeof(float));
  float* part   = (float*)alloc((size_t)STAT_NB*2*256*sizeof(float));
  float* ssb    = (float*)alloc(4*512*sizeof(float));
  u16* h2b = Acat;
  u16* h3b = h1b;
  float* ss1=ssb, *ss2=ssb+512, *ss3=ssb+1024, *ss4=ssb+1536;
  const float ninv = 1.f/(float)N;

  // weight conversions (independent, tiny)
  k_cvt_cat<<<dim3(32), dim3(256), 0, stream>>>(Wl, Wr, Wb1);
  k_cvt_w<<<dim3(32), dim3(256), 0, stream>>>(W1, Wb2, 8192);
  k_cvt_w<<<dim3(8),  dim3(256), 0, stream>>>(W2, Wb3, 2048);
  // x -> bf16 into Acat[:,128:256]
  k_cvt_x<<<dim3(2048), dim3(256), 0, stream>>>(x, Acat, N);

  // CSR build
  k_zero_i32<<<dim3(512), dim3(256), 0, stream>>>(deg, 2*N);
  k_count<<<dim3(1024), dim3(256), 0, stream>>>(ei, E, deg);
  k_scan_block<<<dim3(NB), dim3(256), 0, stream>>>(deg, N, off, blocksum);
  k_scan_sums<<<dim3(1), dim3(512), 0, stream>>>(blocksum, NB, blockoff);
  k_add_off<<<dim3(256), dim3(256), 0, stream>>>(off, blockoff, N);
  k_fill<<<dim3(1024), dim3(256), 0, stream>>>(ei, E, off, cursor, eidx);
  // mean aggregate (bf16 gather) -> Acat[:,0:128]
  k_aggregate<<<dim3((N+3)/4), dim3(256), 0, stream>>>(Acat, off, deg, eidx, N);

  // GEMM1: h1 = Acat @ Wb1^T + bl   (K=256 = [agg|x] vs [Wl|Wr])
  k_gemm_mfma<128><<<dim3(RT2,2), dim3(256), 0, stream>>>(
      Acat, Wb1, (const float*)0, 0, bl, h1b, N, 256, psum, psq);
  k_stats_part<<<dim3(STAT_NB), dim3(256), 0, stream>>>(psum, psq, RT2, 256, part);
  k_stats_fold<<<dim3(1), dim3(256), 0, stream>>>(part, 256, ninv, bn_g, bn_b, ss1);

  // GEMM2: h2 = relu(bn(h1)) @ W1^T + b1
  k_gemm_mfma<128><<<dim3(RT2,2), dim3(256), 0, stream>>>(
      h1b, Wb2, ss1, 1, b1, h2b, N, 256, psum, psq);
  k_stats_part<<<dim3(STAT_NB), dim3(256), 0, stream>>>(psum, psq, RT2, 256, part);
  k_stats_fold<<<dim3(1), dim3(256), 0, stream>>>(part, 256, ninv, g1, bb1, ss2);

  // GEMM3: h3 = relu(bn(h2)) @ W2^T + b2  (hout=64)
  k_gemm_mfma<64><<<dim3(RT2,1), dim3(256), 0, stream>>>(
      h2b, Wb3, ss2, 1, b2, h3b, N, 64, psum, psq);
  k_stats_part<<<dim3(STAT_NB), dim3(256), 0, stream>>>(psum, psq, RT2, 64, part);
  k_stats_fold<<<dim3(1), dim3(64), 0, stream>>>(part, 64, ninv, g2, bb2, ss3);

  // h4 = relu(bn(h3)) @ W3^T + b3   (hout=14)
  k_lin3<<<dim3(RT4), dim3(256), 0, stream>>>(h3b, ss3, W3, b3, h4, N, psum, psq);
  k_stats_part<<<dim3(STAT_NB), dim3(256), 0, stream>>>(psum, psq, RT4, 14, part);
  k_stats_fold<<<dim3(1), dim3(64), 0, stream>>>(part, 14, ninv, g3, bb3, ss4);

  // out = log_softmax(relu(bn(h4)) @ W4^T + b4)
  k_final<<<dim3((N+255)/256), dim3(256), 0, stream>>>(h4, ss4, W4, b4, (float*)d_out, N);
}

// Round 5
// 423.122 us; speedup vs baseline: 5.0530x; 1.2310x over previous
//
#include <hip/hip_runtime.h>
#include <math.h>

#define BN_EPS 1e-5f
#define STAT_NB 64

typedef unsigned short u16;
typedef __attribute__((ext_vector_type(8))) unsigned short u16x8;
typedef __attribute__((ext_vector_type(8))) short bf16x8;
typedef __attribute__((ext_vector_type(4))) float f32x4;

__device__ __forceinline__ float bf2f(u16 b){
  union{unsigned int u; float f;} c; c.u = ((unsigned int)b)<<16; return c.f;
}
__device__ __forceinline__ u16 f2bf(float f){
  union{float f; unsigned int u;} c; c.f=f;
  unsigned int u = c.u;
  return (u16)((u + 0x7fffu + ((u>>16)&1u)) >> 16);
}

// ---------------- CSR build ----------------

__global__ void k_zero_i32(int* __restrict__ p, int n){
  int i = blockIdx.x*blockDim.x + threadIdx.x;
  int stride = gridDim.x*blockDim.x;
  for (; i<n; i+=stride) p[i]=0;
}

__global__ void k_count(const int* __restrict__ ei, int E, int* __restrict__ deg){
  int e = blockIdx.x*blockDim.x + threadIdx.x;
  int stride = gridDim.x*blockDim.x;
  for (; e<E; e+=stride){
    int dst = ei[(size_t)E + e];
    atomicAdd(&deg[dst], 1);
  }
}

__global__ void k_scan_block(const int* __restrict__ deg, int n, int* __restrict__ off, int* __restrict__ blocksum){
  __shared__ int s[256];
  int tid = threadIdx.x;
  int i = blockIdx.x*256 + tid;
  int v = (i<n) ? deg[i] : 0;
  s[tid]=v; __syncthreads();
  #pragma unroll
  for (int o=1;o<256;o<<=1){
    int t = (tid>=o)? s[tid-o] : 0;
    __syncthreads();
    s[tid]+=t;
    __syncthreads();
  }
  if (i<n) off[i] = s[tid]-v;
  if (tid==255) blocksum[blockIdx.x] = s[tid];
}

__global__ void k_scan_sums(const int* __restrict__ blocksum, int nb, int* __restrict__ blockoff){
  __shared__ int s[512];
  int tid = threadIdx.x;
  int v = (tid<nb)? blocksum[tid] : 0;
  s[tid]=v; __syncthreads();
  #pragma unroll
  for (int o=1;o<512;o<<=1){
    int t = (tid>=o)? s[tid-o] : 0;
    __syncthreads();
    s[tid]+=t;
    __syncthreads();
  }
  blockoff[tid] = s[tid]-v;
}

__global__ void k_add_off(int* __restrict__ off, const int* __restrict__ blockoff, int n){
  int i = blockIdx.x*blockDim.x + threadIdx.x;
  int stride = gridDim.x*blockDim.x;
  for (; i<n; i+=stride) off[i] += blockoff[i>>8];
}

__global__ void k_fill(const int* __restrict__ ei, int E, const int* __restrict__ off,
                       int* __restrict__ cursor, int* __restrict__ eidx){
  int e = blockIdx.x*blockDim.x + threadIdx.x;
  int stride = gridDim.x*blockDim.x;
  for (; e<E; e+=stride){
    int src = ei[e];
    int dst = ei[(size_t)E+e];
    int p = atomicAdd(&cursor[dst],1);
    eidx[off[dst]+p] = src;
  }
}

// ---------------- dtype conversion ----------------

// x fp32 [n][128] -> Acat[:,128:256] bf16 (row stride 256)
__global__ void k_cvt_x(const float* __restrict__ x, u16* __restrict__ Acat, int n){
  int i = blockIdx.x*blockDim.x + threadIdx.x;  // one per 8 elems
  int total = n*16;
  int stride = gridDim.x*blockDim.x;
  for (; i<total; i+=stride){
    int r = i>>4, kb = (i&15)*8;
    const float4* src = (const float4*)(x + (size_t)r*128 + kb);
    float4 a = src[0], b = src[1];
    u16x8 v;
    v[0]=f2bf(a.x); v[1]=f2bf(a.y); v[2]=f2bf(a.z); v[3]=f2bf(a.w);
    v[4]=f2bf(b.x); v[5]=f2bf(b.y); v[6]=f2bf(b.z); v[7]=f2bf(b.w);
    *(u16x8*)(Acat + (size_t)r*256 + 128 + kb) = v;
  }
}

// generic fp32 -> bf16 (flat)
__global__ void k_cvt_w(const float* __restrict__ w, u16* __restrict__ wb, int total8){
  int i = blockIdx.x*blockDim.x + threadIdx.x;
  int stride = gridDim.x*blockDim.x;
  for (; i<total8; i+=stride){
    const float4* src = (const float4*)(w + (size_t)i*8);
    float4 a = src[0], b = src[1];
    u16x8 v;
    v[0]=f2bf(a.x); v[1]=f2bf(a.y); v[2]=f2bf(a.z); v[3]=f2bf(a.w);
    v[4]=f2bf(b.x); v[5]=f2bf(b.y); v[6]=f2bf(b.z); v[7]=f2bf(b.w);
    *(u16x8*)(wb + (size_t)i*8) = v;
  }
}

// Wb1[c][k] = k<128 ? Wl[c][k] : Wr[c][k-128]   (c in [0,256))
__global__ void k_cvt_cat(const float* __restrict__ Wl, const float* __restrict__ Wr,
                          u16* __restrict__ Wb1){
  int i = blockIdx.x*blockDim.x + threadIdx.x;  // per 8 elems, total 256*256/8=8192
  if (i >= 8192) return;
  int c = i>>5, kb = (i&31)*8;
  const float* src = (kb<128) ? (Wl + (size_t)c*128 + kb) : (Wr + (size_t)c*128 + kb-128);
  float4 a = ((const float4*)src)[0], b = ((const float4*)src)[1];
  u16x8 v;
  v[0]=f2bf(a.x); v[1]=f2bf(a.y); v[2]=f2bf(a.z); v[3]=f2bf(a.w);
  v[4]=f2bf(b.x); v[5]=f2bf(b.y); v[6]=f2bf(b.z); v[7]=f2bf(b.w);
  *(u16x8*)(Wb1 + (size_t)c*256 + kb) = v;
}

// one wave per node, 8 edge-slots x 8 lanes: mean of bf16 rows
// Acat[s][128:256] -> Acat[wid][0:128].  8 gathers in flight per iteration.
__global__ void k_aggregate(u16* Acat, const int* __restrict__ off,
                            const int* __restrict__ deg, const int* __restrict__ eidx, int n){
  int wid = (blockIdx.x*blockDim.x + threadIdx.x) >> 6;
  int lane = threadIdx.x & 63;
  if (wid >= n) return;
  int o = off[wid], d = deg[wid];
  int eslot = lane >> 3;        // 0..7
  int ck = (lane & 7) * 16;     // 16 channels (32B) per lane
  float f[16];
  #pragma unroll
  for (int j=0;j<16;j++) f[j]=0.f;
  for (int i = eslot; i < d; i += 8){
    int s = eidx[o+i];
    const u16x8* src = (const u16x8*)(Acat + (size_t)s*256 + 128 + ck);
    u16x8 v0 = src[0], v1 = src[1];
    #pragma unroll
    for (int j=0;j<8;j++) f[j]   += bf2f(v0[j]);
    #pragma unroll
    for (int j=0;j<8;j++) f[8+j] += bf2f(v1[j]);
  }
  #pragma unroll
  for (int j=0;j<16;j++){
    f[j] += __shfl_xor(f[j], 8, 64);
    f[j] += __shfl_xor(f[j], 16, 64);
    f[j] += __shfl_xor(f[j], 32, 64);
  }
  if (lane < 8){
    float inv = 1.f/(float)max(d,1);
    u16x8 r0, r1;
    #pragma unroll
    for (int j=0;j<8;j++){ r0[j]=f2bf(f[j]*inv); r1[j]=f2bf(f[8+j]*inv); }
    u16x8* dst = (u16x8*)(Acat + (size_t)wid*256 + ck);
    dst[0]=r0; dst[1]=r1;
  }
}

// ---------------- bf16 MFMA GEMM ----------------
// out[r][c] = sum_k relu?(bn?(A[r][k])) * W[c][k] + bias[c], K=256 fixed
// A,W,out bf16; stats (fp32) emitted per 128-row block.
// tile 128 x COLS, 4 waves (2x2), BK=64, XOR-swizzled LDS (slot ^= row&7).

template<int COLS>
__global__ __launch_bounds__(256) void k_gemm_mfma(
    const u16* __restrict__ A, const u16* __restrict__ W,
    const float* __restrict__ ss, int has_ss,
    const float* __restrict__ bias, u16* __restrict__ out,
    int nrows, int hout,
    float* __restrict__ psum, float* __restrict__ psq)
{
  constexpr int WN  = COLS/2;   // per-wave cols
  constexpr int NFR = WN/16;    // n-fragments per wave
  __shared__ u16 As[128*64];
  __shared__ u16 Bs[COLS*64];
  __shared__ float scs[256], shs[256];
  __shared__ float red[2][2][COLS];

  int tid  = threadIdx.x;
  int lane = tid & 63, wave = tid >> 6;
  int wr = wave >> 1, wc = wave & 1;
  int rbase = blockIdx.x*128, cbase = blockIdx.y*COLS;

  if (has_ss){ scs[tid] = ss[tid]; shs[tid] = ss[256+tid]; }
  __syncthreads();

  f32x4 acc[4][NFR];
  #pragma unroll
  for (int m=0;m<4;m++)
    #pragma unroll
    for (int n=0;n<NFR;n++)
      acc[m][n] = (f32x4){0.f,0.f,0.f,0.f};

  // A staging: thread -> (row, 32-col half); 4 x u16x8 per K-tile
  int arow = tid >> 1;
  int acb  = (tid & 1) * 32;
  bool avalid = (rbase + arow) < nrows;
  const u16* aptr = A + (size_t)(rbase+arow)*256 + acb;
  // B staging
  int brow, bcb;
  if (COLS==128){ brow = tid>>1; bcb = (tid&1)*32; }
  else          { brow = tid>>2; bcb = (tid&3)*16; }
  const u16* bptr = W + (size_t)(cbase+brow)*256 + bcb;

  for (int kt=0; kt<256; kt+=64){
    #pragma unroll
    for (int q=0;q<4;q++){
      u16x8 v = (u16x8){0,0,0,0,0,0,0,0};
      if (avalid) v = *(const u16x8*)(aptr + kt + q*8);
      if (has_ss){
        int k = acb + q*8;  // absolute k = kt + k
        #pragma unroll
        for (int e=0;e<8;e++){
          float f = bf2f(v[e]);
          f = fmaxf(fmaf(f, scs[kt+k+e], shs[kt+k+e]), 0.f);
          v[e] = f2bf(f);
        }
      }
      int slot = ((acb>>3) + q) ^ (arow & 7);
      *(u16x8*)(As + arow*64 + slot*8) = v;
    }
    #pragma unroll
    for (int q=0;q<COLS/32;q++){
      u16x8 v = *(const u16x8*)(bptr + kt + q*8);
      int slot = ((bcb>>3) + q) ^ (brow & 7);
      *(u16x8*)(Bs + brow*64 + slot*8) = v;
    }
    __syncthreads();

    int fr = lane & 15, g = lane >> 4;
    #pragma unroll
    for (int kk=0;kk<2;kk++){
      bf16x8 af[4], bfr[NFR];
      #pragma unroll
      for (int m=0;m<4;m++){
        int row = wr*64 + m*16 + fr;
        int slot = (kk*4 + g) ^ (row & 7);
        af[m] = *(const bf16x8*)(As + row*64 + slot*8);
      }
      #pragma unroll
      for (int n=0;n<NFR;n++){
        int row = wc*WN + n*16 + fr;
        int slot = (kk*4 + g) ^ (row & 7);
        bfr[n] = *(const bf16x8*)(Bs + row*64 + slot*8);
      }
      #pragma unroll
      for (int m=0;m<4;m++)
        #pragma unroll
        for (int n=0;n<NFR;n++)
          acc[m][n] = __builtin_amdgcn_mfma_f32_16x16x32_bf16(af[m], bfr[n], acc[m][n], 0, 0, 0);
    }
    __syncthreads();
  }

  // epilogue: bias, bf16 store, BN partial stats
  int cl = lane & 15, g = lane >> 4;
  float bv[NFR], sn[NFR], qn[NFR];
  #pragma unroll
  for (int n=0;n<NFR;n++){
    bv[n] = bias[cbase + wc*WN + n*16 + cl];
    sn[n] = 0.f; qn[n] = 0.f;
  }
  #pragma unroll
  for (int m=0;m<4;m++){
    int r0 = rbase + wr*64 + m*16 + g*4;
    #pragma unroll
    for (int n=0;n<NFR;n++){
      int c = cbase + wc*WN + n*16 + cl;
      #pragma unroll
      for (int i=0;i<4;i++){
        int r = r0 + i;
        if (r < nrows){
          float v = acc[m][n][i] + bv[n];
          out[(size_t)r*hout + c] = f2bf(v);
          sn[n] += v; qn[n] += v*v;
        }
      }
    }
  }
  #pragma unroll
  for (int n=0;n<NFR;n++){
    sn[n] += __shfl_xor(sn[n], 16, 64);
    sn[n] += __shfl_xor(sn[n], 32, 64);
    qn[n] += __shfl_xor(qn[n], 16, 64);
    qn[n] += __shfl_xor(qn[n], 32, 64);
  }
  if (lane < 16){
    #pragma unroll
    for (int n=0;n<NFR;n++){
      int cc = wc*WN + n*16 + lane;
      red[0][wr][cc] = sn[n];
      red[1][wr][cc] = qn[n];
    }
  }
  __syncthreads();
  if (tid < COLS){
    psum[(size_t)blockIdx.x*hout + cbase + tid] = red[0][0][tid] + red[0][1][tid];
  } else if (tid < 2*COLS){
    int c = tid - COLS;
    psq[(size_t)blockIdx.x*hout + cbase + c] = red[1][0][c] + red[1][1][c];
  }
}

// ---- two-stage deterministic stats fold ----

__global__ __launch_bounds__(256) void k_stats_part(
    const float* __restrict__ psum, const float* __restrict__ psq,
    int rt, int h, float* __restrict__ part){
  int c = threadIdx.x;
  int b = blockIdx.x;
  if (c >= h) return;
  int chunk = (rt + STAT_NB - 1)/STAT_NB;
  int i0 = b*chunk;
  int i1 = min(rt, i0+chunk);
  float s0=0.f,s1=0.f,s2=0.f,s3=0.f, q0=0.f,q1=0.f,q2=0.f,q3=0.f;
  int i=i0;
  for (; i+3<i1; i+=4){
    s0 += psum[(size_t)i*h+c];     q0 += psq[(size_t)i*h+c];
    s1 += psum[(size_t)(i+1)*h+c]; q1 += psq[(size_t)(i+1)*h+c];
    s2 += psum[(size_t)(i+2)*h+c]; q2 += psq[(size_t)(i+2)*h+c];
    s3 += psum[(size_t)(i+3)*h+c]; q3 += psq[(size_t)(i+3)*h+c];
  }
  for (; i<i1; ++i){ s0 += psum[(size_t)i*h+c]; q0 += psq[(size_t)i*h+c]; }
  part[((size_t)b*2  )*h + c] = (s0+s1)+(s2+s3);
  part[((size_t)b*2+1)*h + c] = (q0+q1)+(q2+q3);
}

__global__ void k_stats_fold(const float* __restrict__ part, int h, float ninv,
                             const float* __restrict__ g, const float* __restrict__ b_,
                             float* __restrict__ ss){
  int c = threadIdx.x;
  if (c >= h) return;
  float S0=0.f,S1=0.f,Q0=0.f,Q1=0.f;
  #pragma unroll 2
  for (int b=0;b<STAT_NB;b+=2){
    S0 += part[((size_t)b*2  )*h + c];
    Q0 += part[((size_t)b*2+1)*h + c];
    S1 += part[((size_t)(b+1)*2  )*h + c];
    Q1 += part[((size_t)(b+1)*2+1)*h + c];
  }
  float S = S0+S1, Q = Q0+Q1;
  float m = S*ninv;
  float v = fmaxf(Q*ninv - m*m, 0.f);
  float sc = g[c] * rsqrtf(v + BN_EPS);
  ss[c]   = sc;
  ss[h+c] = b_[c] - m*sc;
}

// 64 -> 14 linear (bf16 input, weights in LDS), fused BN+relu, emits stats
__global__ __launch_bounds__(256) void k_lin3(const u16* __restrict__ h3, const float* __restrict__ ss3,
     const float* __restrict__ W3, const float* __restrict__ b3,
     float* __restrict__ h4, int n, float* __restrict__ psum, float* __restrict__ psq){
  __shared__ float Ws[14*64];
  __shared__ float bs[14];
  __shared__ float sc[64], sh[64];
  __shared__ float redp[2][14][4];
  int tid=threadIdx.x;
  for (int i=tid;i<896;i+=256) Ws[i]=W3[i];
  if (tid<14) bs[tid]=b3[tid];
  if (tid<64){ sc[tid]=ss3[tid]; sh[tid]=ss3[64+tid]; }
  __syncthreads();
  int node = blockIdx.x*256 + tid;
  float o[14];
  #pragma unroll
  for (int hh=0;hh<14;hh++) o[hh]=0.f;
  if (node<n){
    const u16x8* ar = (const u16x8*)(h3 + (size_t)node*64);
    #pragma unroll
    for (int kv=0;kv<8;kv++){
      u16x8 v = ar[kv];
      #pragma unroll
      for (int j=0;j<8;j++){
        int k=kv*8+j;
        float a = fmaxf(fmaf(bf2f(v[j]), sc[k], sh[k]), 0.f);
        #pragma unroll
        for (int hh=0;hh<14;hh++) o[hh] = fmaf(a, Ws[hh*64+k], o[hh]);
      }
    }
    #pragma unroll
    for (int hh=0;hh<14;hh++){ o[hh]+=bs[hh]; h4[(size_t)node*14+hh]=o[hh]; }
  }
  int lane = tid & 63, w = tid>>6;
  #pragma unroll
  for (int hh=0;hh<14;hh++){
    float sv = (node<n)? o[hh] : 0.f;
    float qv = sv*sv;
    #pragma unroll
    for (int offs=32;offs>0;offs>>=1){
      sv += __shfl_down(sv,offs,64);
      qv += __shfl_down(qv,offs,64);
    }
    if (lane==0){ redp[0][hh][w]=sv; redp[1][hh][w]=qv; }
  }
  __syncthreads();
  if (tid<14){
    float t=redp[0][tid][0]+redp[0][tid][1]+redp[0][tid][2]+redp[0][tid][3];
    psum[(size_t)blockIdx.x*14+tid]=t;
  } else if (tid>=64 && tid<78){
    int c=tid-64;
    float t=redp[1][c][0]+redp[1][c][1]+redp[1][c][2]+redp[1][c][3];
    psq[(size_t)blockIdx.x*14+c]=t;
  }
}

// 14 -> 2 + log_softmax
__global__ void k_final(const float* __restrict__ h4, const float* __restrict__ ss4,
   const float* __restrict__ W4, const float* __restrict__ b4, float* __restrict__ out, int n){
  int node = blockIdx.x*blockDim.x+threadIdx.x;
  if (node>=n) return;
  float z0=b4[0], z1=b4[1];
  #pragma unroll
  for (int j=0;j<14;j++){
    float a = fmaxf(h4[(size_t)node*14+j]*ss4[j]+ss4[14+j], 0.f);
    z0 = fmaf(a, W4[j],    z0);
    z1 = fmaf(a, W4[14+j], z1);
  }
  float m = fmaxf(z0,z1);
  float lse = m + logf(expf(z0-m)+expf(z1-m));
  out[(size_t)node*2]   = z0-lse;
  out[(size_t)node*2+1] = z1-lse;
}

extern "C" void kernel_launch(void* const* d_in, const int* in_sizes, int n_in,
                              void* d_out, int out_size, void* d_ws, size_t ws_size,
                              hipStream_t stream){
  const float* x    = (const float*)d_in[0];
  const int*   ei   = (const int*)d_in[1];          // int64 in ref -> int32 on device per harness
  const float* Wl   = (const float*)d_in[2];
  const float* bl   = (const float*)d_in[3];
  const float* Wr   = (const float*)d_in[4];
  const float* bn_g = (const float*)d_in[5];
  const float* bn_b = (const float*)d_in[6];
  const float* W1   = (const float*)d_in[7];
  const float* b1   = (const float*)d_in[8];
  const float* W2   = (const float*)d_in[9];
  const float* b2   = (const float*)d_in[10];
  const float* W3   = (const float*)d_in[11];
  const float* b3   = (const float*)d_in[12];
  const float* W4   = (const float*)d_in[13];
  const float* b4   = (const float*)d_in[14];
  const float* g1   = (const float*)d_in[15];
  const float* bb1  = (const float*)d_in[16];
  const float* g2   = (const float*)d_in[17];
  const float* bb2  = (const float*)d_in[18];
  const float* g3   = (const float*)d_in[19];
  const float* bb3  = (const float*)d_in[20];

  const int N = in_sizes[0]/128;
  const int E = in_sizes[1]/2;
  const int RT2 = (N+127)/128;   // 128-row GEMM tiles
  const int RT4 = (N+255)/256;   // lin3 blocks
  const int NB  = (N+255)/256;

  char* p = (char*)d_ws;
  auto alloc = [&](size_t bytes)->void*{
    void* r = (void*)p;
    p += (bytes + 255) & ~(size_t)255;
    return r;
  };
  int* deg      = (int*)alloc((size_t)N*2*sizeof(int)); // deg + cursor contiguous
  int* cursor   = deg + N;
  int* off      = (int*)alloc((size_t)N*sizeof(int));
  int* blocksum = (int*)alloc(512*sizeof(int));
  int* blockoff = (int*)alloc(512*sizeof(int));
  int* eidx     = (int*)alloc((size_t)E*sizeof(int));
  u16* Acat     = (u16*)alloc((size_t)N*256*sizeof(u16));  // [agg | x] bf16; reused as h2
  u16* h1b      = (u16*)alloc((size_t)N*256*sizeof(u16));  // gemm1 out; reused as h3
  float* h4     = (float*)alloc((size_t)N*14*sizeof(float));
  u16* Wb1      = (u16*)alloc(256*256*sizeof(u16));
  u16* Wb2      = (u16*)alloc(256*256*sizeof(u16));
  u16* Wb3      = (u16*)alloc(64*256*sizeof(u16));
  float* psum   = (float*)alloc((size_t)RT2*256*sizeof(float));
  float* psq    = (float*)alloc((size_t)RT2*256*sizeof(float));
  float* part   = (float*)alloc((size_t)STAT_NB*2*256*sizeof(float));
  float* ssb    = (float*)alloc(4*512*sizeof(float));
  u16* h2b = Acat;
  u16* h3b = h1b;
  float* ss1=ssb, *ss2=ssb+512, *ss3=ssb+1024, *ss4=ssb+1536;
  const float ninv = 1.f/(float)N;

  // weight conversions (independent, tiny)
  k_cvt_cat<<<dim3(32), dim3(256), 0, stream>>>(Wl, Wr, Wb1);
  k_cvt_w<<<dim3(32), dim3(256), 0, stream>>>(W1, Wb2, 8192);
  k_cvt_w<<<dim3(8),  dim3(256), 0, stream>>>(W2, Wb3, 2048);
  // x -> bf16 into Acat[:,128:256]
  k_cvt_x<<<dim3(2048), dim3(256), 0, stream>>>(x, Acat, N);

  // CSR build
  k_zero_i32<<<dim3(512), dim3(256), 0, stream>>>(deg, 2*N);
  k_count<<<dim3(1024), dim3(256), 0, stream>>>(ei, E, deg);
  k_scan_block<<<dim3(NB), dim3(256), 0, stream>>>(deg, N, off, blocksum);
  k_scan_sums<<<dim3(1), dim3(512), 0, stream>>>(blocksum, NB, blockoff);
  k_add_off<<<dim3(256), dim3(256), 0, stream>>>(off, blockoff, N);
  k_fill<<<dim3(1024), dim3(256), 0, stream>>>(ei, E, off, cursor, eidx);
  // mean aggregate (bf16 gather, 8-way edge-parallel) -> Acat[:,0:128]
  k_aggregate<<<dim3((N+3)/4), dim3(256), 0, stream>>>(Acat, off, deg, eidx, N);

  // GEMM1: h1 = Acat @ Wb1^T + bl   (K=256 = [agg|x] vs [Wl|Wr])
  k_gemm_mfma<128><<<dim3(RT2,2), dim3(256), 0, stream>>>(
      Acat, Wb1, (const float*)0, 0, bl, h1b, N, 256, psum, psq);
  k_stats_part<<<dim3(STAT_NB), dim3(256), 0, stream>>>(psum, psq, RT2, 256, part);
  k_stats_fold<<<dim3(1), dim3(256), 0, stream>>>(part, 256, ninv, bn_g, bn_b, ss1);

  // GEMM2: h2 = relu(bn(h1)) @ W1^T + b1
  k_gemm_mfma<128><<<dim3(RT2,2), dim3(256), 0, stream>>>(
      h1b, Wb2, ss1, 1, b1, h2b, N, 256, psum, psq);
  k_stats_part<<<dim3(STAT_NB), dim3(256), 0, stream>>>(psum, psq, RT2, 256, part);
  k_stats_fold<<<dim3(1), dim3(256), 0, stream>>>(part, 256, ninv, g1, bb1, ss2);

  // GEMM3: h3 = relu(bn(h2)) @ W2^T + b2  (hout=64)
  k_gemm_mfma<64><<<dim3(RT2,1), dim3(256), 0, stream>>>(
      h2b, Wb3, ss2, 1, b2, h3b, N, 64, psum, psq);
  k_stats_part<<<dim3(STAT_NB), dim3(256), 0, stream>>>(psum, psq, RT2, 64, part);
  k_stats_fold<<<dim3(1), dim3(64), 0, stream>>>(part, 64, ninv, g2, bb2, ss3);

  // h4 = relu(bn(h3)) @ W3^T + b3   (hout=14)
  k_lin3<<<dim3(RT4), dim3(256), 0, stream>>>(h3b, ss3, W3, b3, h4, N, psum, psq);
  k_stats_part<<<dim3(STAT_NB), dim3(256), 0, stream>>>(psum, psq, RT4, 14, part);
  k_stats_fold<<<dim3(1), dim3(64), 0, stream>>>(part, 14, ninv, g3, bb3, ss4);

  // out = log_softmax(relu(bn(h4)) @ W4^T + b4)
  k_final<<<dim3((N+255)/256), dim3(256), 0, stream>>>(h4, ss4, W4, b4, (float*)d_out, N);
}

// Round 6
// 417.619 us; speedup vs baseline: 5.1196x; 1.0132x over previous
//
#include <hip/hip_runtime.h>
#include <math.h>

#define BN_EPS 1e-5f
#define STAT_NB 64

typedef unsigned short u16;
typedef __attribute__((ext_vector_type(8))) unsigned short u16x8;
typedef __attribute__((ext_vector_type(8))) short bf16x8;
typedef __attribute__((ext_vector_type(4))) float f32x4;

__device__ __forceinline__ float bf2f(u16 b){
  union{unsigned int u; float f;} c; c.u = ((unsigned int)b)<<16; return c.f;
}
__device__ __forceinline__ u16 f2bf(float f){
  union{float f; unsigned int u;} c; c.f=f;
  unsigned int u = c.u;
  return (u16)((u + 0x7fffu + ((u>>16)&1u)) >> 16);
}

// ---------------- CSR build ----------------

__global__ void k_zero_i32(int* __restrict__ p, int n){
  int i = blockIdx.x*blockDim.x + threadIdx.x;
  int stride = gridDim.x*blockDim.x;
  for (; i<n; i+=stride) p[i]=0;
}

__global__ void k_count(const int* __restrict__ ei, int E, int* __restrict__ deg){
  int e = blockIdx.x*blockDim.x + threadIdx.x;
  int stride = gridDim.x*blockDim.x;
  for (; e<E; e+=stride){
    int dst = ei[(size_t)E + e];
    atomicAdd(&deg[dst], 1);
  }
}

__global__ void k_scan_block(const int* __restrict__ deg, int n, int* __restrict__ off, int* __restrict__ blocksum){
  __shared__ int s[256];
  int tid = threadIdx.x;
  int i = blockIdx.x*256 + tid;
  int v = (i<n) ? deg[i] : 0;
  s[tid]=v; __syncthreads();
  #pragma unroll
  for (int o=1;o<256;o<<=1){
    int t = (tid>=o)? s[tid-o] : 0;
    __syncthreads();
    s[tid]+=t;
    __syncthreads();
  }
  if (i<n) off[i] = s[tid]-v;
  if (tid==255) blocksum[blockIdx.x] = s[tid];
}

__global__ void k_scan_sums(const int* __restrict__ blocksum, int nb, int* __restrict__ blockoff){
  __shared__ int s[512];
  int tid = threadIdx.x;
  int v = (tid<nb)? blocksum[tid] : 0;
  s[tid]=v; __syncthreads();
  #pragma unroll
  for (int o=1;o<512;o<<=1){
    int t = (tid>=o)? s[tid-o] : 0;
    __syncthreads();
    s[tid]+=t;
    __syncthreads();
  }
  blockoff[tid] = s[tid]-v;
}

__global__ void k_add_off(int* __restrict__ off, const int* __restrict__ blockoff, int n){
  int i = blockIdx.x*blockDim.x + threadIdx.x;
  int stride = gridDim.x*blockDim.x;
  for (; i<n; i+=stride) off[i] += blockoff[i>>8];
}

// dst-sharded fill: shard s (= bid&7) owns dst range [s*ns, (s+1)*ns);
// its 64 workers (bid>>3) collectively scan all edges and commit in-range ones.
// Under round-robin block->XCD dispatch all writers of an eidx region live on
// one XCD -> eidx lines accumulate writes in that L2 (kills 64B/4B write amp).
__global__ void k_fill_shard(const int* __restrict__ ei, int E, int n,
                             const int* __restrict__ off, int* __restrict__ cursor,
                             int* __restrict__ eidx){
  int s = blockIdx.x & 7;
  int w = blockIdx.x >> 3;
  int ns = (n + 7) / 8;
  int lo = s * ns, hi = min(n, lo + ns);
  int per = (E + 63) / 64;
  int e0 = w * per, e1 = min(E, e0 + per);
  for (int e = e0 + threadIdx.x; e < e1; e += 256){
    int dst = ei[(size_t)E + e];
    if (dst >= lo && dst < hi){
      int src = ei[e];
      int p = atomicAdd(&cursor[dst], 1);
      eidx[off[dst] + p] = src;
    }
  }
}

// ---------------- dtype conversion ----------------

// x fp32 [n][128] -> Acat[:,128:256] bf16 (row stride 256)
__global__ void k_cvt_x(const float* __restrict__ x, u16* __restrict__ Acat, int n){
  int i = blockIdx.x*blockDim.x + threadIdx.x;  // one per 8 elems
  int total = n*16;
  int stride = gridDim.x*blockDim.x;
  for (; i<total; i+=stride){
    int r = i>>4, kb = (i&15)*8;
    const float4* src = (const float4*)(x + (size_t)r*128 + kb);
    float4 a = src[0], b = src[1];
    u16x8 v;
    v[0]=f2bf(a.x); v[1]=f2bf(a.y); v[2]=f2bf(a.z); v[3]=f2bf(a.w);
    v[4]=f2bf(b.x); v[5]=f2bf(b.y); v[6]=f2bf(b.z); v[7]=f2bf(b.w);
    *(u16x8*)(Acat + (size_t)r*256 + 128 + kb) = v;
  }
}

// generic fp32 -> bf16 (flat)
__global__ void k_cvt_w(const float* __restrict__ w, u16* __restrict__ wb, int total8){
  int i = blockIdx.x*blockDim.x + threadIdx.x;
  int stride = gridDim.x*blockDim.x;
  for (; i<total8; i+=stride){
    const float4* src = (const float4*)(w + (size_t)i*8);
    float4 a = src[0], b = src[1];
    u16x8 v;
    v[0]=f2bf(a.x); v[1]=f2bf(a.y); v[2]=f2bf(a.z); v[3]=f2bf(a.w);
    v[4]=f2bf(b.x); v[5]=f2bf(b.y); v[6]=f2bf(b.z); v[7]=f2bf(b.w);
    *(u16x8*)(wb + (size_t)i*8) = v;
  }
}

// Wb1[c][k] = k<128 ? Wl[c][k] : Wr[c][k-128]   (c in [0,256))
__global__ void k_cvt_cat(const float* __restrict__ Wl, const float* __restrict__ Wr,
                          u16* __restrict__ Wb1){
  int i = blockIdx.x*blockDim.x + threadIdx.x;  // per 8 elems, total 256*256/8=8192
  if (i >= 8192) return;
  int c = i>>5, kb = (i&31)*8;
  const float* src = (kb<128) ? (Wl + (size_t)c*128 + kb) : (Wr + (size_t)c*128 + kb-128);
  float4 a = ((const float4*)src)[0], b = ((const float4*)src)[1];
  u16x8 v;
  v[0]=f2bf(a.x); v[1]=f2bf(a.y); v[2]=f2bf(a.z); v[3]=f2bf(a.w);
  v[4]=f2bf(b.x); v[5]=f2bf(b.y); v[6]=f2bf(b.z); v[7]=f2bf(b.w);
  *(u16x8*)(Wb1 + (size_t)c*256 + kb) = v;
}

// one wave per node, 8 edge-slots x 8 lanes: mean of bf16 rows
// Acat[s][128:256] -> Acat[wid][0:128].  8 gathers in flight per iteration.
__global__ void k_aggregate(u16* Acat, const int* __restrict__ off,
                            const int* __restrict__ deg, const int* __restrict__ eidx, int n){
  int wid = (blockIdx.x*blockDim.x + threadIdx.x) >> 6;
  int lane = threadIdx.x & 63;
  if (wid >= n) return;
  int o = off[wid], d = deg[wid];
  int eslot = lane >> 3;        // 0..7
  int ck = (lane & 7) * 16;     // 16 channels (32B) per lane
  float f[16];
  #pragma unroll
  for (int j=0;j<16;j++) f[j]=0.f;
  for (int i = eslot; i < d; i += 8){
    int s = eidx[o+i];
    const u16x8* src = (const u16x8*)(Acat + (size_t)s*256 + 128 + ck);
    u16x8 v0 = src[0], v1 = src[1];
    #pragma unroll
    for (int j=0;j<8;j++) f[j]   += bf2f(v0[j]);
    #pragma unroll
    for (int j=0;j<8;j++) f[8+j] += bf2f(v1[j]);
  }
  #pragma unroll
  for (int j=0;j<16;j++){
    f[j] += __shfl_xor(f[j], 8, 64);
    f[j] += __shfl_xor(f[j], 16, 64);
    f[j] += __shfl_xor(f[j], 32, 64);
  }
  if (lane < 8){
    float inv = 1.f/(float)max(d,1);
    u16x8 r0, r1;
    #pragma unroll
    for (int j=0;j<8;j++){ r0[j]=f2bf(f[j]*inv); r1[j]=f2bf(f[8+j]*inv); }
    u16x8* dst = (u16x8*)(Acat + (size_t)wid*256 + ck);
    dst[0]=r0; dst[1]=r1;
  }
}

// ---------------- bf16 MFMA GEMM ----------------
// out[r][c] = sum_k relu?(bn?(A[r][k])) * W[c][k] + bias[c], K=256 fixed
// A,W,out bf16; stats (fp32) emitted per 128-row block.
// tile 128 x COLS, 4 waves (2x2), BK=64, XOR-swizzled LDS (slot ^= row&7).

template<int COLS>
__global__ __launch_bounds__(256) void k_gemm_mfma(
    const u16* __restrict__ A, const u16* __restrict__ W,
    const float* __restrict__ ss, int has_ss,
    const float* __restrict__ bias, u16* __restrict__ out,
    int nrows, int hout,
    float* __restrict__ psum, float* __restrict__ psq)
{
  constexpr int WN  = COLS/2;   // per-wave cols
  constexpr int NFR = WN/16;    // n-fragments per wave
  __shared__ u16 As[128*64];
  __shared__ u16 Bs[COLS*64];
  __shared__ float scs[256], shs[256];
  __shared__ float red[2][2][COLS];

  int tid  = threadIdx.x;
  int lane = tid & 63, wave = tid >> 6;
  int wr = wave >> 1, wc = wave & 1;
  int rbase = blockIdx.x*128, cbase = blockIdx.y*COLS;

  if (has_ss){ scs[tid] = ss[tid]; shs[tid] = ss[256+tid]; }
  __syncthreads();

  f32x4 acc[4][NFR];
  #pragma unroll
  for (int m=0;m<4;m++)
    #pragma unroll
    for (int n=0;n<NFR;n++)
      acc[m][n] = (f32x4){0.f,0.f,0.f,0.f};

  // A staging: thread -> (row, 32-col half); 4 x u16x8 per K-tile
  int arow = tid >> 1;
  int acb  = (tid & 1) * 32;
  bool avalid = (rbase + arow) < nrows;
  const u16* aptr = A + (size_t)(rbase+arow)*256 + acb;
  // B staging
  int brow, bcb;
  if (COLS==128){ brow = tid>>1; bcb = (tid&1)*32; }
  else          { brow = tid>>2; bcb = (tid&3)*16; }
  const u16* bptr = W + (size_t)(cbase+brow)*256 + bcb;

  for (int kt=0; kt<256; kt+=64){
    #pragma unroll
    for (int q=0;q<4;q++){
      u16x8 v = (u16x8){0,0,0,0,0,0,0,0};
      if (avalid) v = *(const u16x8*)(aptr + kt + q*8);
      if (has_ss){
        int k = acb + q*8;  // absolute k = kt + k
        #pragma unroll
        for (int e=0;e<8;e++){
          float f = bf2f(v[e]);
          f = fmaxf(fmaf(f, scs[kt+k+e], shs[kt+k+e]), 0.f);
          v[e] = f2bf(f);
        }
      }
      int slot = ((acb>>3) + q) ^ (arow & 7);
      *(u16x8*)(As + arow*64 + slot*8) = v;
    }
    #pragma unroll
    for (int q=0;q<COLS/32;q++){
      u16x8 v = *(const u16x8*)(bptr + kt + q*8);
      int slot = ((bcb>>3) + q) ^ (brow & 7);
      *(u16x8*)(Bs + brow*64 + slot*8) = v;
    }
    __syncthreads();

    int fr = lane & 15, g = lane >> 4;
    #pragma unroll
    for (int kk=0;kk<2;kk++){
      bf16x8 af[4], bfr[NFR];
      #pragma unroll
      for (int m=0;m<4;m++){
        int row = wr*64 + m*16 + fr;
        int slot = (kk*4 + g) ^ (row & 7);
        af[m] = *(const bf16x8*)(As + row*64 + slot*8);
      }
      #pragma unroll
      for (int n=0;n<NFR;n++){
        int row = wc*WN + n*16 + fr;
        int slot = (kk*4 + g) ^ (row & 7);
        bfr[n] = *(const bf16x8*)(Bs + row*64 + slot*8);
      }
      #pragma unroll
      for (int m=0;m<4;m++)
        #pragma unroll
        for (int n=0;n<NFR;n++)
          acc[m][n] = __builtin_amdgcn_mfma_f32_16x16x32_bf16(af[m], bfr[n], acc[m][n], 0, 0, 0);
    }
    __syncthreads();
  }

  // epilogue: bias, bf16 store, BN partial stats
  int cl = lane & 15, g = lane >> 4;
  float bv[NFR], sn[NFR], qn[NFR];
  #pragma unroll
  for (int n=0;n<NFR;n++){
    bv[n] = bias[cbase + wc*WN + n*16 + cl];
    sn[n] = 0.f; qn[n] = 0.f;
  }
  #pragma unroll
  for (int m=0;m<4;m++){
    int r0 = rbase + wr*64 + m*16 + g*4;
    #pragma unroll
    for (int n=0;n<NFR;n++){
      int c = cbase + wc*WN + n*16 + cl;
      #pragma unroll
      for (int i=0;i<4;i++){
        int r = r0 + i;
        if (r < nrows){
          float v = acc[m][n][i] + bv[n];
          out[(size_t)r*hout + c] = f2bf(v);
          sn[n] += v; qn[n] += v*v;
        }
      }
    }
  }
  #pragma unroll
  for (int n=0;n<NFR;n++){
    sn[n] += __shfl_xor(sn[n], 16, 64);
    sn[n] += __shfl_xor(sn[n], 32, 64);
    qn[n] += __shfl_xor(qn[n], 16, 64);
    qn[n] += __shfl_xor(qn[n], 32, 64);
  }
  if (lane < 16){
    #pragma unroll
    for (int n=0;n<NFR;n++){
      int cc = wc*WN + n*16 + lane;
      red[0][wr][cc] = sn[n];
      red[1][wr][cc] = qn[n];
    }
  }
  __syncthreads();
  if (tid < COLS){
    psum[(size_t)blockIdx.x*hout + cbase + tid] = red[0][0][tid] + red[0][1][tid];
  } else if (tid < 2*COLS){
    int c = tid - COLS;
    psq[(size_t)blockIdx.x*hout + cbase + c] = red[1][0][c] + red[1][1][c];
  }
}

// ---- two-stage deterministic stats fold ----

__global__ __launch_bounds__(256) void k_stats_part(
    const float* __restrict__ psum, const float* __restrict__ psq,
    int rt, int h, float* __restrict__ part){
  int c = threadIdx.x;
  int b = blockIdx.x;
  if (c >= h) return;
  int chunk = (rt + STAT_NB - 1)/STAT_NB;
  int i0 = b*chunk;
  int i1 = min(rt, i0+chunk);
  float s0=0.f,s1=0.f,s2=0.f,s3=0.f, q0=0.f,q1=0.f,q2=0.f,q3=0.f;
  int i=i0;
  for (; i+3<i1; i+=4){
    s0 += psum[(size_t)i*h+c];     q0 += psq[(size_t)i*h+c];
    s1 += psum[(size_t)(i+1)*h+c]; q1 += psq[(size_t)(i+1)*h+c];
    s2 += psum[(size_t)(i+2)*h+c]; q2 += psq[(size_t)(i+2)*h+c];
    s3 += psum[(size_t)(i+3)*h+c]; q3 += psq[(size_t)(i+3)*h+c];
  }
  for (; i<i1; ++i){ s0 += psum[(size_t)i*h+c]; q0 += psq[(size_t)i*h+c]; }
  part[((size_t)b*2  )*h + c] = (s0+s1)+(s2+s3);
  part[((size_t)b*2+1)*h + c] = (q0+q1)+(q2+q3);
}

__global__ void k_stats_fold(const float* __restrict__ part, int h, float ninv,
                             const float* __restrict__ g, const float* __restrict__ b_,
                             float* __restrict__ ss){
  int c = threadIdx.x;
  if (c >= h) return;
  float S0=0.f,S1=0.f,Q0=0.f,Q1=0.f;
  #pragma unroll 2
  for (int b=0;b<STAT_NB;b+=2){
    S0 += part[((size_t)b*2  )*h + c];
    Q0 += part[((size_t)b*2+1)*h + c];
    S1 += part[((size_t)(b+1)*2  )*h + c];
    Q1 += part[((size_t)(b+1)*2+1)*h + c];
  }
  float S = S0+S1, Q = Q0+Q1;
  float m = S*ninv;
  float v = fmaxf(Q*ninv - m*m, 0.f);
  float sc = g[c] * rsqrtf(v + BN_EPS);
  ss[c]   = sc;
  ss[h+c] = b_[c] - m*sc;
}

// 64 -> 14 linear (bf16 input, weights in LDS), fused BN+relu, emits stats
__global__ __launch_bounds__(256) void k_lin3(const u16* __restrict__ h3, const float* __restrict__ ss3,
     const float* __restrict__ W3, const float* __restrict__ b3,
     float* __restrict__ h4, int n, float* __restrict__ psum, float* __restrict__ psq){
  __shared__ float Ws[14*64];
  __shared__ float bs[14];
  __shared__ float sc[64], sh[64];
  __shared__ float redp[2][14][4];
  int tid=threadIdx.x;
  for (int i=tid;i<896;i+=256) Ws[i]=W3[i];
  if (tid<14) bs[tid]=b3[tid];
  if (tid<64){ sc[tid]=ss3[tid]; sh[tid]=ss3[64+tid]; }
  __syncthreads();
  int node = blockIdx.x*256 + tid;
  float o[14];
  #pragma unroll
  for (int hh=0;hh<14;hh++) o[hh]=0.f;
  if (node<n){
    const u16x8* ar = (const u16x8*)(h3 + (size_t)node*64);
    #pragma unroll
    for (int kv=0;kv<8;kv++){
      u16x8 v = ar[kv];
      #pragma unroll
      for (int j=0;j<8;j++){
        int k=kv*8+j;
        float a = fmaxf(fmaf(bf2f(v[j]), sc[k], sh[k]), 0.f);
        #pragma unroll
        for (int hh=0;hh<14;hh++) o[hh] = fmaf(a, Ws[hh*64+k], o[hh]);
      }
    }
    #pragma unroll
    for (int hh=0;hh<14;hh++){ o[hh]+=bs[hh]; h4[(size_t)node*14+hh]=o[hh]; }
  }
  int lane = tid & 63, w = tid>>6;
  #pragma unroll
  for (int hh=0;hh<14;hh++){
    float sv = (node<n)? o[hh] : 0.f;
    float qv = sv*sv;
    #pragma unroll
    for (int offs=32;offs>0;offs>>=1){
      sv += __shfl_down(sv,offs,64);
      qv += __shfl_down(qv,offs,64);
    }
    if (lane==0){ redp[0][hh][w]=sv; redp[1][hh][w]=qv; }
  }
  __syncthreads();
  if (tid<14){
    float t=redp[0][tid][0]+redp[0][tid][1]+redp[0][tid][2]+redp[0][tid][3];
    psum[(size_t)blockIdx.x*14+tid]=t;
  } else if (tid>=64 && tid<78){
    int c=tid-64;
    float t=redp[1][c][0]+redp[1][c][1]+redp[1][c][2]+redp[1][c][3];
    psq[(size_t)blockIdx.x*14+c]=t;
  }
}

// 14 -> 2 + log_softmax
__global__ void k_final(const float* __restrict__ h4, const float* __restrict__ ss4,
   const float* __restrict__ W4, const float* __restrict__ b4, float* __restrict__ out, int n){
  int node = blockIdx.x*blockDim.x+threadIdx.x;
  if (node>=n) return;
  float z0=b4[0], z1=b4[1];
  #pragma unroll
  for (int j=0;j<14;j++){
    float a = fmaxf(h4[(size_t)node*14+j]*ss4[j]+ss4[14+j], 0.f);
    z0 = fmaf(a, W4[j],    z0);
    z1 = fmaf(a, W4[14+j], z1);
  }
  float m = fmaxf(z0,z1);
  float lse = m + logf(expf(z0-m)+expf(z1-m));
  out[(size_t)node*2]   = z0-lse;
  out[(size_t)node*2+1] = z1-lse;
}

extern "C" void kernel_launch(void* const* d_in, const int* in_sizes, int n_in,
                              void* d_out, int out_size, void* d_ws, size_t ws_size,
                              hipStream_t stream){
  const float* x    = (const float*)d_in[0];
  const int*   ei   = (const int*)d_in[1];          // int64 in ref -> int32 on device per harness
  const float* Wl   = (const float*)d_in[2];
  const float* bl   = (const float*)d_in[3];
  const float* Wr   = (const float*)d_in[4];
  const float* bn_g = (const float*)d_in[5];
  const float* bn_b = (const float*)d_in[6];
  const float* W1   = (const float*)d_in[7];
  const float* b1   = (const float*)d_in[8];
  const float* W2   = (const float*)d_in[9];
  const float* b2   = (const float*)d_in[10];
  const float* W3   = (const float*)d_in[11];
  const float* b3   = (const float*)d_in[12];
  const float* W4   = (const float*)d_in[13];
  const float* b4   = (const float*)d_in[14];
  const float* g1   = (const float*)d_in[15];
  const float* bb1  = (const float*)d_in[16];
  const float* g2   = (const float*)d_in[17];
  const float* bb2  = (const float*)d_in[18];
  const float* g3   = (const float*)d_in[19];
  const float* bb3  = (const float*)d_in[20];

  const int N = in_sizes[0]/128;
  const int E = in_sizes[1]/2;
  const int RT2 = (N+127)/128;   // 128-row GEMM tiles
  const int RT4 = (N+255)/256;   // lin3 blocks
  const int NB  = (N+255)/256;

  char* p = (char*)d_ws;
  auto alloc = [&](size_t bytes)->void*{
    void* r = (void*)p;
    p += (bytes + 255) & ~(size_t)255;
    return r;
  };
  int* deg      = (int*)alloc((size_t)N*2*sizeof(int)); // deg + cursor contiguous
  int* cursor   = deg + N;
  int* off      = (int*)alloc((size_t)N*sizeof(int));
  int* blocksum = (int*)alloc(512*sizeof(int));
  int* blockoff = (int*)alloc(512*sizeof(int));
  int* eidx     = (int*)alloc((size_t)E*sizeof(int));
  u16* Acat     = (u16*)alloc((size_t)N*256*sizeof(u16));  // [agg | x] bf16; reused as h2
  u16* h1b      = (u16*)alloc((size_t)N*256*sizeof(u16));  // gemm1 out; reused as h3
  float* h4     = (float*)alloc((size_t)N*14*sizeof(float));
  u16* Wb1      = (u16*)alloc(256*256*sizeof(u16));
  u16* Wb2      = (u16*)alloc(256*256*sizeof(u16));
  u16* Wb3      = (u16*)alloc(64*256*sizeof(u16));
  float* psum   = (float*)alloc((size_t)RT2*256*sizeof(float));
  float* psq    = (float*)alloc((size_t)RT2*256*sizeof(float));
  float* part   = (float*)alloc((size_t)STAT_NB*2*256*sizeof(float));
  float* ssb    = (float*)alloc(4*512*sizeof(float));
  u16* h2b = Acat;
  u16* h3b = h1b;
  float* ss1=ssb, *ss2=ssb+512, *ss3=ssb+1024, *ss4=ssb+1536;
  const float ninv = 1.f/(float)N;

  // weight conversions (independent, tiny)
  k_cvt_cat<<<dim3(32), dim3(256), 0, stream>>>(Wl, Wr, Wb1);
  k_cvt_w<<<dim3(32), dim3(256), 0, stream>>>(W1, Wb2, 8192);
  k_cvt_w<<<dim3(8),  dim3(256), 0, stream>>>(W2, Wb3, 2048);
  // x -> bf16 into Acat[:,128:256]
  k_cvt_x<<<dim3(2048), dim3(256), 0, stream>>>(x, Acat, N);

  // CSR build
  k_zero_i32<<<dim3(512), dim3(256), 0, stream>>>(deg, 2*N);
  k_count<<<dim3(1024), dim3(256), 0, stream>>>(ei, E, deg);
  k_scan_block<<<dim3(NB), dim3(256), 0, stream>>>(deg, N, off, blocksum);
  k_scan_sums<<<dim3(1), dim3(512), 0, stream>>>(blocksum, NB, blockoff);
  k_add_off<<<dim3(256), dim3(256), 0, stream>>>(off, blockoff, N);
  k_fill_shard<<<dim3(512), dim3(256), 0, stream>>>(ei, E, N, off, cursor, eidx);
  // mean aggregate (bf16 gather, 8-way edge-parallel) -> Acat[:,0:128]
  k_aggregate<<<dim3((N+3)/4), dim3(256), 0, stream>>>(Acat, off, deg, eidx, N);

  // GEMM1: h1 = Acat @ Wb1^T + bl   (K=256 = [agg|x] vs [Wl|Wr])
  k_gemm_mfma<128><<<dim3(RT2,2), dim3(256), 0, stream>>>(
      Acat, Wb1, (const float*)0, 0, bl, h1b, N, 256, psum, psq);
  k_stats_part<<<dim3(STAT_NB), dim3(256), 0, stream>>>(psum, psq, RT2, 256, part);
  k_stats_fold<<<dim3(1), dim3(256), 0, stream>>>(part, 256, ninv, bn_g, bn_b, ss1);

  // GEMM2: h2 = relu(bn(h1)) @ W1^T + b1
  k_gemm_mfma<128><<<dim3(RT2,2), dim3(256), 0, stream>>>(
      h1b, Wb2, ss1, 1, b1, h2b, N, 256, psum, psq);
  k_stats_part<<<dim3(STAT_NB), dim3(256), 0, stream>>>(psum, psq, RT2, 256, part);
  k_stats_fold<<<dim3(1), dim3(256), 0, stream>>>(part, 256, ninv, g1, bb1, ss2);

  // GEMM3: h3 = relu(bn(h2)) @ W2^T + b2  (hout=64)
  k_gemm_mfma<64><<<dim3(RT2,1), dim3(256), 0, stream>>>(
      h2b, Wb3, ss2, 1, b2, h3b, N, 64, psum, psq);
  k_stats_part<<<dim3(STAT_NB), dim3(256), 0, stream>>>(psum, psq, RT2, 64, part);
  k_stats_fold<<<dim3(1), dim3(64), 0, stream>>>(part, 64, ninv, g2, bb2, ss3);

  // h4 = relu(bn(h3)) @ W3^T + b3   (hout=14)
  k_lin3<<<dim3(RT4), dim3(256), 0, stream>>>(h3b, ss3, W3, b3, h4, N, psum, psq);
  k_stats_part<<<dim3(STAT_NB), dim3(256), 0, stream>>>(psum, psq, RT4, 14, part);
  k_stats_fold<<<dim3(1), dim3(64), 0, stream>>>(part, 14, ninv, g3, bb3, ss4);

  // out = log_softmax(relu(bn(h4)) @ W4^T + b4)
  k_final<<<dim3((N+255)/256), dim3(256), 0, stream>>>(h4, ss4, W4, b4, (float*)d_out, N);
}

// Round 7
// 351.699 us; speedup vs baseline: 6.0792x; 1.1874x over previous
//
#include <hip/hip_runtime.h>
#include <math.h>

#define BN_EPS 1e-5f
#define STAT_NB 64
#define GBIN 512           // blocks in binning passes
#define BSH 7              // nodes-per-bucket shift (128)

typedef unsigned short u16;
typedef __attribute__((ext_vector_type(8))) unsigned short u16x8;
typedef __attribute__((ext_vector_type(8))) short bf16x8;
typedef __attribute__((ext_vector_type(4))) float f32x4;

__device__ __forceinline__ float bf2f(u16 b){
  union{unsigned int u; float f;} c; c.u = ((unsigned int)b)<<16; return c.f;
}
__device__ __forceinline__ u16 f2bf(float f){
  union{float f; unsigned int u;} c; c.f=f;
  unsigned int u = c.u;
  return (u16)((u + 0x7fffu + ((u>>16)&1u)) >> 16);
}

// ---------------- CSR build via radix partition (no per-edge global atomics,
// no random 4B scatter to cold lines) ----------------

// A1: per-block LDS histogram of dst buckets -> blkhist[b*GBIN + blk]
__global__ __launch_bounds__(256) void k_hist(const int* __restrict__ ei, int E, int nbkt,
                                              int* __restrict__ blkhist){
  __shared__ int hist[1024];
  int tid = threadIdx.x, blk = blockIdx.x;
  for (int b=tid;b<1024;b+=256) hist[b]=0;
  __syncthreads();
  int per = (E + GBIN - 1)/GBIN;
  int e0 = blk*per, e1 = min(E, e0+per);
  for (int e=e0+tid; e<e1; e+=256)
    atomicAdd(&hist[ei[(size_t)E+e]>>BSH], 1);
  __syncthreads();
  for (int b=tid;b<nbkt;b+=256) blkhist[(size_t)b*GBIN + blk] = hist[b];
}

// A2a: per-bucket exclusive prefix over its GBIN block counts (in place);
// bucket total -> bbase[b]
__global__ void k_rowscan(int* __restrict__ blkhist, int nbkt, int* __restrict__ bbase){
  int b = blockIdx.x*blockDim.x + threadIdx.x;
  if (b >= nbkt) return;
  int run = 0;
  for (int k=0;k<GBIN;k++){
    size_t idx = (size_t)b*GBIN + k;
    int t = blkhist[idx];
    blkhist[idx] = run;
    run += t;
  }
  bbase[b] = run;
}

// A2b: exclusive scan of bucket totals (single block, nbkt<=1024), sentinel=E
__global__ void k_bscan(int* __restrict__ bbase, int nbkt){
  __shared__ int s[1024];
  int tid = threadIdx.x;
  int v = (tid<nbkt)? bbase[tid] : 0;
  s[tid]=v; __syncthreads();
  #pragma unroll
  for (int o=1;o<1024;o<<=1){
    int t = (tid>=o)? s[tid-o] : 0;
    __syncthreads();
    s[tid]+=t;
    __syncthreads();
  }
  if (tid<nbkt) bbase[tid] = s[tid]-v;
  if (tid==1023) bbase[nbkt] = s[1023];
}

// A3: scatter packed pairs (src<<BSH | dst&127) into per-(block,bucket)
// exclusive consecutive ranges via LDS cursors -> near-sequential writes
__global__ __launch_bounds__(256) void k_scatter(const int* __restrict__ ei, int E, int nbkt,
                                                 const int* __restrict__ blkhist,
                                                 const int* __restrict__ bbase,
                                                 int* __restrict__ pairs){
  __shared__ int cur[1024];
  int tid = threadIdx.x, blk = blockIdx.x;
  for (int b=tid;b<nbkt;b+=256) cur[b] = bbase[b] + blkhist[(size_t)b*GBIN + blk];
  __syncthreads();
  int per = (E + GBIN - 1)/GBIN;
  int e0 = blk*per, e1 = min(E, e0+per);
  for (int e=e0+tid; e<e1; e+=256){
    int dst = ei[(size_t)E+e];
    int src = ei[e];
    int b = dst>>BSH;
    int p = atomicAdd(&cur[b], 1);
    pairs[p] = (src<<BSH) | (dst & 127);
  }
}

// B: one block per bucket: counting-sort pairs -> eidx (single-writer region),
// emit deg/off directly (no global scans).
__global__ __launch_bounds__(256) void k_bucket_csr(const int* __restrict__ pairs,
                                                    const int* __restrict__ bbase,
                                                    int nbkt, int n,
                                                    int* __restrict__ deg, int* __restrict__ off,
                                                    int* __restrict__ eidx){
  __shared__ int hist[128], loff[128], cur2[128];
  int tid = threadIdx.x, b = blockIdx.x;
  if (b >= nbkt) return;
  int n0 = b<<BSH;
  int nn = min(128, n - n0);
  int e0 = bbase[b], e1 = bbase[b+1];
  int cnt = e1 - e0;
  if (tid<128) hist[tid]=0;
  __syncthreads();
  for (int i=tid;i<cnt;i+=256)
    atomicAdd(&hist[pairs[e0+i] & 127], 1);
  __syncthreads();
  int hv=0;
  if (tid<128){ hv = hist[tid]; loff[tid] = hv; }
  __syncthreads();
  #pragma unroll
  for (int o=1;o<128;o<<=1){
    int t = (tid<128 && tid>=o)? loff[tid-o] : 0;
    __syncthreads();
    if (tid<128) loff[tid]+=t;
    __syncthreads();
  }
  if (tid<128){
    int ex = loff[tid]-hv;
    cur2[tid] = ex;
    if (tid<nn){
      deg[n0+tid] = hv;
      off[n0+tid] = e0 + ex;
    }
  }
  __syncthreads();
  for (int i=tid;i<cnt;i+=256){
    int v = pairs[e0+i];
    int p = atomicAdd(&cur2[v & 127], 1);
    eidx[e0 + p] = v>>BSH;
  }
}

// ---------------- dtype conversion ----------------

// x fp32 [n][128] -> Acat[:,128:256] bf16 (row stride 256)
__global__ void k_cvt_x(const float* __restrict__ x, u16* __restrict__ Acat, int n){
  int i = blockIdx.x*blockDim.x + threadIdx.x;  // one per 8 elems
  int total = n*16;
  int stride = gridDim.x*blockDim.x;
  for (; i<total; i+=stride){
    int r = i>>4, kb = (i&15)*8;
    const float4* src = (const float4*)(x + (size_t)r*128 + kb);
    float4 a = src[0], b = src[1];
    u16x8 v;
    v[0]=f2bf(a.x); v[1]=f2bf(a.y); v[2]=f2bf(a.z); v[3]=f2bf(a.w);
    v[4]=f2bf(b.x); v[5]=f2bf(b.y); v[6]=f2bf(b.z); v[7]=f2bf(b.w);
    *(u16x8*)(Acat + (size_t)r*256 + 128 + kb) = v;
  }
}

// generic fp32 -> bf16 (flat)
__global__ void k_cvt_w(const float* __restrict__ w, u16* __restrict__ wb, int total8){
  int i = blockIdx.x*blockDim.x + threadIdx.x;
  int stride = gridDim.x*blockDim.x;
  for (; i<total8; i+=stride){
    const float4* src = (const float4*)(w + (size_t)i*8);
    float4 a = src[0], b = src[1];
    u16x8 v;
    v[0]=f2bf(a.x); v[1]=f2bf(a.y); v[2]=f2bf(a.z); v[3]=f2bf(a.w);
    v[4]=f2bf(b.x); v[5]=f2bf(b.y); v[6]=f2bf(b.z); v[7]=f2bf(b.w);
    *(u16x8*)(wb + (size_t)i*8) = v;
  }
}

// Wb1[c][k] = k<128 ? Wl[c][k] : Wr[c][k-128]   (c in [0,256))
__global__ void k_cvt_cat(const float* __restrict__ Wl, const float* __restrict__ Wr,
                          u16* __restrict__ Wb1){
  int i = blockIdx.x*blockDim.x + threadIdx.x;  // per 8 elems, total 256*256/8=8192
  if (i >= 8192) return;
  int c = i>>5, kb = (i&31)*8;
  const float* src = (kb<128) ? (Wl + (size_t)c*128 + kb) : (Wr + (size_t)c*128 + kb-128);
  float4 a = ((const float4*)src)[0], b = ((const float4*)src)[1];
  u16x8 v;
  v[0]=f2bf(a.x); v[1]=f2bf(a.y); v[2]=f2bf(a.z); v[3]=f2bf(a.w);
  v[4]=f2bf(b.x); v[5]=f2bf(b.y); v[6]=f2bf(b.z); v[7]=f2bf(b.w);
  *(u16x8*)(Wb1 + (size_t)c*256 + kb) = v;
}

// one wave per node, 8 edge-slots x 8 lanes: mean of bf16 rows
// Acat[s][128:256] -> Acat[wid][0:128].  8 gathers in flight per iteration.
__global__ void k_aggregate(u16* Acat, const int* __restrict__ off,
                            const int* __restrict__ deg, const int* __restrict__ eidx, int n){
  int wid = (blockIdx.x*blockDim.x + threadIdx.x) >> 6;
  int lane = threadIdx.x & 63;
  if (wid >= n) return;
  int o = off[wid], d = deg[wid];
  int eslot = lane >> 3;        // 0..7
  int ck = (lane & 7) * 16;     // 16 channels (32B) per lane
  float f[16];
  #pragma unroll
  for (int j=0;j<16;j++) f[j]=0.f;
  for (int i = eslot; i < d; i += 8){
    int s = eidx[o+i];
    const u16x8* src = (const u16x8*)(Acat + (size_t)s*256 + 128 + ck);
    u16x8 v0 = src[0], v1 = src[1];
    #pragma unroll
    for (int j=0;j<8;j++) f[j]   += bf2f(v0[j]);
    #pragma unroll
    for (int j=0;j<8;j++) f[8+j] += bf2f(v1[j]);
  }
  #pragma unroll
  for (int j=0;j<16;j++){
    f[j] += __shfl_xor(f[j], 8, 64);
    f[j] += __shfl_xor(f[j], 16, 64);
    f[j] += __shfl_xor(f[j], 32, 64);
  }
  if (lane < 8){
    float inv = 1.f/(float)max(d,1);
    u16x8 r0, r1;
    #pragma unroll
    for (int j=0;j<8;j++){ r0[j]=f2bf(f[j]*inv); r1[j]=f2bf(f[8+j]*inv); }
    u16x8* dst = (u16x8*)(Acat + (size_t)wid*256 + ck);
    dst[0]=r0; dst[1]=r1;
  }
}

// ---------------- bf16 MFMA GEMM ----------------
// out[r][c] = sum_k relu?(bn?(A[r][k])) * W[c][k] + bias[c], K=256 fixed
// A,W,out bf16; stats (fp32) emitted per 128-row block.
// tile 128 x COLS, 4 waves (2x2), BK=64, XOR-swizzled LDS (slot ^= row&7).

template<int COLS>
__global__ __launch_bounds__(256) void k_gemm_mfma(
    const u16* __restrict__ A, const u16* __restrict__ W,
    const float* __restrict__ ss, int has_ss,
    const float* __restrict__ bias, u16* __restrict__ out,
    int nrows, int hout,
    float* __restrict__ psum, float* __restrict__ psq)
{
  constexpr int WN  = COLS/2;   // per-wave cols
  constexpr int NFR = WN/16;    // n-fragments per wave
  __shared__ u16 As[128*64];
  __shared__ u16 Bs[COLS*64];
  __shared__ float scs[256], shs[256];
  __shared__ float red[2][2][COLS];

  int tid  = threadIdx.x;
  int lane = tid & 63, wave = tid >> 6;
  int wr = wave >> 1, wc = wave & 1;
  int rbase = blockIdx.x*128, cbase = blockIdx.y*COLS;

  if (has_ss){ scs[tid] = ss[tid]; shs[tid] = ss[256+tid]; }
  __syncthreads();

  f32x4 acc[4][NFR];
  #pragma unroll
  for (int m=0;m<4;m++)
    #pragma unroll
    for (int n=0;n<NFR;n++)
      acc[m][n] = (f32x4){0.f,0.f,0.f,0.f};

  // A staging: thread -> (row, 32-col half); 4 x u16x8 per K-tile
  int arow = tid >> 1;
  int acb  = (tid & 1) * 32;
  bool avalid = (rbase + arow) < nrows;
  const u16* aptr = A + (size_t)(rbase+arow)*256 + acb;
  // B staging
  int brow, bcb;
  if (COLS==128){ brow = tid>>1; bcb = (tid&1)*32; }
  else          { brow = tid>>2; bcb = (tid&3)*16; }
  const u16* bptr = W + (size_t)(cbase+brow)*256 + bcb;

  for (int kt=0; kt<256; kt+=64){
    #pragma unroll
    for (int q=0;q<4;q++){
      u16x8 v = (u16x8){0,0,0,0,0,0,0,0};
      if (avalid) v = *(const u16x8*)(aptr + kt + q*8);
      if (has_ss){
        int k = acb + q*8;  // absolute k = kt + k
        #pragma unroll
        for (int e=0;e<8;e++){
          float f = bf2f(v[e]);
          f = fmaxf(fmaf(f, scs[kt+k+e], shs[kt+k+e]), 0.f);
          v[e] = f2bf(f);
        }
      }
      int slot = ((acb>>3) + q) ^ (arow & 7);
      *(u16x8*)(As + arow*64 + slot*8) = v;
    }
    #pragma unroll
    for (int q=0;q<COLS/32;q++){
      u16x8 v = *(const u16x8*)(bptr + kt + q*8);
      int slot = ((bcb>>3) + q) ^ (brow & 7);
      *(u16x8*)(Bs + brow*64 + slot*8) = v;
    }
    __syncthreads();

    int fr = lane & 15, g = lane >> 4;
    #pragma unroll
    for (int kk=0;kk<2;kk++){
      bf16x8 af[4], bfr[NFR];
      #pragma unroll
      for (int m=0;m<4;m++){
        int row = wr*64 + m*16 + fr;
        int slot = (kk*4 + g) ^ (row & 7);
        af[m] = *(const bf16x8*)(As + row*64 + slot*8);
      }
      #pragma unroll
      for (int n=0;n<NFR;n++){
        int row = wc*WN + n*16 + fr;
        int slot = (kk*4 + g) ^ (row & 7);
        bfr[n] = *(const bf16x8*)(Bs + row*64 + slot*8);
      }
      #pragma unroll
      for (int m=0;m<4;m++)
        #pragma unroll
        for (int n=0;n<NFR;n++)
          acc[m][n] = __builtin_amdgcn_mfma_f32_16x16x32_bf16(af[m], bfr[n], acc[m][n], 0, 0, 0);
    }
    __syncthreads();
  }

  // epilogue: bias, bf16 store, BN partial stats
  int cl = lane & 15, g = lane >> 4;
  float bv[NFR], sn[NFR], qn[NFR];
  #pragma unroll
  for (int n=0;n<NFR;n++){
    bv[n] = bias[cbase + wc*WN + n*16 + cl];
    sn[n] = 0.f; qn[n] = 0.f;
  }
  #pragma unroll
  for (int m=0;m<4;m++){
    int r0 = rbase + wr*64 + m*16 + g*4;
    #pragma unroll
    for (int n=0;n<NFR;n++){
      int c = cbase + wc*WN + n*16 + cl;
      #pragma unroll
      for (int i=0;i<4;i++){
        int r = r0 + i;
        if (r < nrows){
          float v = acc[m][n][i] + bv[n];
          out[(size_t)r*hout + c] = f2bf(v);
          sn[n] += v; qn[n] += v*v;
        }
      }
    }
  }
  #pragma unroll
  for (int n=0;n<NFR;n++){
    sn[n] += __shfl_xor(sn[n], 16, 64);
    sn[n] += __shfl_xor(sn[n], 32, 64);
    qn[n] += __shfl_xor(qn[n], 16, 64);
    qn[n] += __shfl_xor(qn[n], 32, 64);
  }
  if (lane < 16){
    #pragma unroll
    for (int n=0;n<NFR;n++){
      int cc = wc*WN + n*16 + lane;
      red[0][wr][cc] = sn[n];
      red[1][wr][cc] = qn[n];
    }
  }
  __syncthreads();
  if (tid < COLS){
    psum[(size_t)blockIdx.x*hout + cbase + tid] = red[0][0][tid] + red[0][1][tid];
  } else if (tid < 2*COLS){
    int c = tid - COLS;
    psq[(size_t)blockIdx.x*hout + cbase + c] = red[1][0][c] + red[1][1][c];
  }
}

// ---- two-stage deterministic stats fold ----

__global__ __launch_bounds__(256) void k_stats_part(
    const float* __restrict__ psum, const float* __restrict__ psq,
    int rt, int h, float* __restrict__ part){
  int c = threadIdx.x;
  int b = blockIdx.x;
  if (c >= h) return;
  int chunk = (rt + STAT_NB - 1)/STAT_NB;
  int i0 = b*chunk;
  int i1 = min(rt, i0+chunk);
  float s0=0.f,s1=0.f,s2=0.f,s3=0.f, q0=0.f,q1=0.f,q2=0.f,q3=0.f;
  int i=i0;
  for (; i+3<i1; i+=4){
    s0 += psum[(size_t)i*h+c];     q0 += psq[(size_t)i*h+c];
    s1 += psum[(size_t)(i+1)*h+c]; q1 += psq[(size_t)(i+1)*h+c];
    s2 += psum[(size_t)(i+2)*h+c]; q2 += psq[(size_t)(i+2)*h+c];
    s3 += psum[(size_t)(i+3)*h+c]; q3 += psq[(size_t)(i+3)*h+c];
  }
  for (; i<i1; ++i){ s0 += psum[(size_t)i*h+c]; q0 += psq[(size_t)i*h+c]; }
  part[((size_t)b*2  )*h + c] = (s0+s1)+(s2+s3);
  part[((size_t)b*2+1)*h + c] = (q0+q1)+(q2+q3);
}

__global__ void k_stats_fold(const float* __restrict__ part, int h, float ninv,
                             const float* __restrict__ g, const float* __restrict__ b_,
                             float* __restrict__ ss){
  int c = threadIdx.x;
  if (c >= h) return;
  float S0=0.f,S1=0.f,Q0=0.f,Q1=0.f;
  #pragma unroll 2
  for (int b=0;b<STAT_NB;b+=2){
    S0 += part[((size_t)b*2  )*h + c];
    Q0 += part[((size_t)b*2+1)*h + c];
    S1 += part[((size_t)(b+1)*2  )*h + c];
    Q1 += part[((size_t)(b+1)*2+1)*h + c];
  }
  float S = S0+S1, Q = Q0+Q1;
  float m = S*ninv;
  float v = fmaxf(Q*ninv - m*m, 0.f);
  float sc = g[c] * rsqrtf(v + BN_EPS);
  ss[c]   = sc;
  ss[h+c] = b_[c] - m*sc;
}

// 64 -> 14 linear (bf16 input, weights in LDS), fused BN+relu, emits stats
__global__ __launch_bounds__(256) void k_lin3(const u16* __restrict__ h3, const float* __restrict__ ss3,
     const float* __restrict__ W3, const float* __restrict__ b3,
     float* __restrict__ h4, int n, float* __restrict__ psum, float* __restrict__ psq){
  __shared__ float Ws[14*64];
  __shared__ float bs[14];
  __shared__ float sc[64], sh[64];
  __shared__ float redp[2][14][4];
  int tid=threadIdx.x;
  for (int i=tid;i<896;i+=256) Ws[i]=W3[i];
  if (tid<14) bs[tid]=b3[tid];
  if (tid<64){ sc[tid]=ss3[tid]; sh[tid]=ss3[64+tid]; }
  __syncthreads();
  int node = blockIdx.x*256 + tid;
  float o[14];
  #pragma unroll
  for (int hh=0;hh<14;hh++) o[hh]=0.f;
  if (node<n){
    const u16x8* ar = (const u16x8*)(h3 + (size_t)node*64);
    #pragma unroll
    for (int kv=0;kv<8;kv++){
      u16x8 v = ar[kv];
      #pragma unroll
      for (int j=0;j<8;j++){
        int k=kv*8+j;
        float a = fmaxf(fmaf(bf2f(v[j]), sc[k], sh[k]), 0.f);
        #pragma unroll
        for (int hh=0;hh<14;hh++) o[hh] = fmaf(a, Ws[hh*64+k], o[hh]);
      }
    }
    #pragma unroll
    for (int hh=0;hh<14;hh++){ o[hh]+=bs[hh]; h4[(size_t)node*14+hh]=o[hh]; }
  }
  int lane = tid & 63, w = tid>>6;
  #pragma unroll
  for (int hh=0;hh<14;hh++){
    float sv = (node<n)? o[hh] : 0.f;
    float qv = sv*sv;
    #pragma unroll
    for (int offs=32;offs>0;offs>>=1){
      sv += __shfl_down(sv,offs,64);
      qv += __shfl_down(qv,offs,64);
    }
    if (lane==0){ redp[0][hh][w]=sv; redp[1][hh][w]=qv; }
  }
  __syncthreads();
  if (tid<14){
    float t=redp[0][tid][0]+redp[0][tid][1]+redp[0][tid][2]+redp[0][tid][3];
    psum[(size_t)blockIdx.x*14+tid]=t;
  } else if (tid>=64 && tid<78){
    int c=tid-64;
    float t=redp[1][c][0]+redp[1][c][1]+redp[1][c][2]+redp[1][c][3];
    psq[(size_t)blockIdx.x*14+c]=t;
  }
}

// 14 -> 2 + log_softmax
__global__ void k_final(const float* __restrict__ h4, const float* __restrict__ ss4,
   const float* __restrict__ W4, const float* __restrict__ b4, float* __restrict__ out, int n){
  int node = blockIdx.x*blockDim.x+threadIdx.x;
  if (node>=n) return;
  float z0=b4[0], z1=b4[1];
  #pragma unroll
  for (int j=0;j<14;j++){
    float a = fmaxf(h4[(size_t)node*14+j]*ss4[j]+ss4[14+j], 0.f);
    z0 = fmaf(a, W4[j],    z0);
    z1 = fmaf(a, W4[14+j], z1);
  }
  float m = fmaxf(z0,z1);
  float lse = m + logf(expf(z0-m)+expf(z1-m));
  out[(size_t)node*2]   = z0-lse;
  out[(size_t)node*2+1] = z1-lse;
}

extern "C" void kernel_launch(void* const* d_in, const int* in_sizes, int n_in,
                              void* d_out, int out_size, void* d_ws, size_t ws_size,
                              hipStream_t stream){
  const float* x    = (const float*)d_in[0];
  const int*   ei   = (const int*)d_in[1];          // int64 in ref -> int32 on device per harness
  const float* Wl   = (const float*)d_in[2];
  const float* bl   = (const float*)d_in[3];
  const float* Wr   = (const float*)d_in[4];
  const float* bn_g = (const float*)d_in[5];
  const float* bn_b = (const float*)d_in[6];
  const float* W1   = (const float*)d_in[7];
  const float* b1   = (const float*)d_in[8];
  const float* W2   = (const float*)d_in[9];
  const float* b2   = (const float*)d_in[10];
  const float* W3   = (const float*)d_in[11];
  const float* b3   = (const float*)d_in[12];
  const float* W4   = (const float*)d_in[13];
  const float* b4   = (const float*)d_in[14];
  const float* g1   = (const float*)d_in[15];
  const float* bb1  = (const float*)d_in[16];
  const float* g2   = (const float*)d_in[17];
  const float* bb2  = (const float*)d_in[18];
  const float* g3   = (const float*)d_in[19];
  const float* bb3  = (const float*)d_in[20];

  const int N = in_sizes[0]/128;
  const int E = in_sizes[1]/2;
  const int NBKT = (N + 127) >> BSH;     // 128 nodes per bucket
  const int RT2 = (N+127)/128;   // 128-row GEMM tiles
  const int RT4 = (N+255)/256;   // lin3 blocks

  char* p = (char*)d_ws;
  auto alloc = [&](size_t bytes)->void*{
    void* r = (void*)p;
    p += (bytes + 255) & ~(size_t)255;
    return r;
  };
  int* deg      = (int*)alloc((size_t)N*sizeof(int));
  int* off      = (int*)alloc((size_t)N*sizeof(int));
  int* bbase    = (int*)alloc(1025*sizeof(int));
  int* blkhist  = (int*)alloc((size_t)1024*GBIN*sizeof(int));
  int* pairs    = (int*)alloc((size_t)E*sizeof(int));
  int* eidx     = (int*)alloc((size_t)E*sizeof(int));
  u16* Acat     = (u16*)alloc((size_t)N*256*sizeof(u16));  // [agg | x] bf16; reused as h2
  u16* h1b      = (u16*)alloc((size_t)N*256*sizeof(u16));  // gemm1 out; reused as h3
  float* h4     = (float*)alloc((size_t)N*14*sizeof(float));
  u16* Wb1      = (u16*)alloc(256*256*sizeof(u16));
  u16* Wb2      = (u16*)alloc(256*256*sizeof(u16));
  u16* Wb3      = (u16*)alloc(64*256*sizeof(u16));
  float* psum   = (float*)alloc((size_t)RT2*256*sizeof(float));
  float* psq    = (float*)alloc((size_t)RT2*256*sizeof(float));
  float* part   = (float*)alloc((size_t)STAT_NB*2*256*sizeof(float));
  float* ssb    = (float*)alloc(4*512*sizeof(float));
  u16* h2b = Acat;
  u16* h3b = h1b;
  float* ss1=ssb, *ss2=ssb+512, *ss3=ssb+1024, *ss4=ssb+1536;
  const float ninv = 1.f/(float)N;

  // weight conversions (independent, tiny)
  k_cvt_cat<<<dim3(32), dim3(256), 0, stream>>>(Wl, Wr, Wb1);
  k_cvt_w<<<dim3(32), dim3(256), 0, stream>>>(W1, Wb2, 8192);
  k_cvt_w<<<dim3(8),  dim3(256), 0, stream>>>(W2, Wb3, 2048);
  // x -> bf16 into Acat[:,128:256]
  k_cvt_x<<<dim3(2048), dim3(256), 0, stream>>>(x, Acat, N);

  // CSR build: histogram -> scans -> partition scatter -> per-bucket sort
  k_hist<<<dim3(GBIN), dim3(256), 0, stream>>>(ei, E, NBKT, blkhist);
  k_rowscan<<<dim3((NBKT+255)/256), dim3(256), 0, stream>>>(blkhist, NBKT, bbase);
  k_bscan<<<dim3(1), dim3(1024), 0, stream>>>(bbase, NBKT);
  k_scatter<<<dim3(GBIN), dim3(256), 0, stream>>>(ei, E, NBKT, blkhist, bbase, pairs);
  k_bucket_csr<<<dim3(NBKT), dim3(256), 0, stream>>>(pairs, bbase, NBKT, N, deg, off, eidx);

  // mean aggregate (bf16 gather, 8-way edge-parallel) -> Acat[:,0:128]
  k_aggregate<<<dim3((N+3)/4), dim3(256), 0, stream>>>(Acat, off, deg, eidx, N);

  // GEMM1: h1 = Acat @ Wb1^T + bl   (K=256 = [agg|x] vs [Wl|Wr])
  k_gemm_mfma<128><<<dim3(RT2,2), dim3(256), 0, stream>>>(
      Acat, Wb1, (const float*)0, 0, bl, h1b, N, 256, psum, psq);
  k_stats_part<<<dim3(STAT_NB), dim3(256), 0, stream>>>(psum, psq, RT2, 256, part);
  k_stats_fold<<<dim3(1), dim3(256), 0, stream>>>(part, 256, ninv, bn_g, bn_b, ss1);

  // GEMM2: h2 = relu(bn(h1)) @ W1^T + b1
  k_gemm_mfma<128><<<dim3(RT2,2), dim3(256), 0, stream>>>(
      h1b, Wb2, ss1, 1, b1, h2b, N, 256, psum, psq);
  k_stats_part<<<dim3(STAT_NB), dim3(256), 0, stream>>>(psum, psq, RT2, 256, part);
  k_stats_fold<<<dim3(1), dim3(256), 0, stream>>>(part, 256, ninv, g1, bb1, ss2);

  // GEMM3: h3 = relu(bn(h2)) @ W2^T + b2  (hout=64)
  k_gemm_mfma<64><<<dim3(RT2,1), dim3(256), 0, stream>>>(
      h2b, Wb3, ss2, 1, b2, h3b, N, 64, psum, psq);
  k_stats_part<<<dim3(STAT_NB), dim3(256), 0, stream>>>(psum, psq, RT2, 64, part);
  k_stats_fold<<<dim3(1), dim3(64), 0, stream>>>(part, 64, ninv, g2, bb2, ss3);

  // h4 = relu(bn(h3)) @ W3^T + b3   (hout=14)
  k_lin3<<<dim3(RT4), dim3(256), 0, stream>>>(h3b, ss3, W3, b3, h4, N, psum, psq);
  k_stats_part<<<dim3(STAT_NB), dim3(256), 0, stream>>>(psum, psq, RT4, 14, part);
  k_stats_fold<<<dim3(1), dim3(64), 0, stream>>>(part, 14, ninv, g3, bb3, ss4);

  // out = log_softmax(relu(bn(h4)) @ W4^T + b4)
  k_final<<<dim3((N+255)/256), dim3(256), 0, stream>>>(h4, ss4, W4, b4, (float*)d_out, N);
}